// Round 1
// baseline (3482.938 us; speedup 1.0000x reference)
//
#include <hip/hip_runtime.h>

#define T_ 64
#define B_ 32
#define P_ 32
#define N_ 1024
#define H_ 128
#define G_ 512   // 4*H

__device__ __forceinline__ float sigm(float x){ return 1.f/(1.f+__expf(-x)); }

// ---------------- Kernel 0: fold input projections, transpose weights ----------------
__global__ __launch_bounds__(256) void prep_kernel(
    const float* __restrict__ W_sp, const float* __restrict__ b_sp,
    const float* __restrict__ W_st, const float* __restrict__ b_st,
    const float* __restrict__ Wih_t, const float* __restrict__ Whh_t,
    const float* __restrict__ bih_t, const float* __restrict__ bhh_t,
    const float* __restrict__ Wih_s, const float* __restrict__ Whh_s,
    const float* __restrict__ bih_s, const float* __restrict__ bhh_s,
    const float* __restrict__ F1, const float* __restrict__ F2,
    float* __restrict__ M_t, float* __restrict__ bias_t,
    float* __restrict__ M_s, float* __restrict__ bias_s,
    float* __restrict__ WhhT_t, float* __restrict__ WhhT_s,
    float* __restrict__ F1T, float* __restrict__ F2T)
{
  int tid = threadIdx.x;
  int blk = blockIdx.x;
  if (blk == 0) {
    for (int g = tid; g < G_; g += 256) {
      float m0=0.f,m1=0.f,bt=0.f;
      for (int e=0;e<H_;e++){ float w=Wih_t[g*H_+e]; m0+=w*W_sp[e*2]; m1+=w*W_sp[e*2+1]; bt+=w*b_sp[e]; }
      M_t[g*2+0]=m0; M_t[g*2+1]=m1; bias_t[g]=bt+bih_t[g]+bhh_t[g];
      float s0=0.f,s1=0.f,s2=0.f,s3=0.f,bs=0.f;
      for (int e=0;e<H_;e++){ float w=Wih_s[g*H_+e]; s0+=w*W_st[e*4]; s1+=w*W_st[e*4+1]; s2+=w*W_st[e*4+2]; s3+=w*W_st[e*4+3]; bs+=w*b_st[e]; }
      M_s[g*4+0]=s0; M_s[g*4+1]=s1; M_s[g*4+2]=s2; M_s[g*4+3]=s3; bias_s[g]=bs+bih_s[g]+bhh_s[g];
    }
  } else if (blk == 1) {
    for (int idx = tid; idx < G_*H_; idx += 256) {
      int g = idx >> 7, k = idx & 127;
      WhhT_t[k*G_+g] = Whh_t[idx];
      WhhT_s[k*G_+g] = Whh_s[idx];
    }
  } else if (blk == 2) {
    for (int idx = tid; idx < H_*2*H_; idx += 256) { // F1 (128,256)
      int j = idx >> 8, k = idx & 255;
      F1T[k*H_+j] = F1[idx];
    }
  } else {
    for (int idx = tid; idx < H_*H_; idx += 256) {  // F2 (128,128)
      int j = idx >> 7, k = idx & 127;
      F2T[k*H_+j] = F2[idx];
    }
  }
}

// ---------------- Kernel 1: both masked LSTMs, 8 rows per block ----------------
// blockIdx.x: row chunk (n0 = x*8), blockIdx.y: 0 = traj LSTM, 1 = state LSTM
// thread: r = tid>>5 (row in chunk), l = tid&31; owns hidden j = 4*l..4*l+3
__global__ __launch_bounds__(256) void lstm_kernel(
    const float* __restrict__ rel, const float* __restrict__ pvx,
    const float* __restrict__ pvy, const float* __restrict__ pax,
    const float* __restrict__ pay, const int* __restrict__ maskI,
    const float* __restrict__ M_t, const float* __restrict__ bias_t, const float* __restrict__ WhhT_t,
    const float* __restrict__ M_s, const float* __restrict__ bias_s, const float* __restrict__ WhhT_s,
    float* __restrict__ h_t_out, float* __restrict__ h_s_out, float* __restrict__ okb)
{
  const int lstm = blockIdx.y;
  const int tid = threadIdx.x;
  const int r = tid >> 5, l = tid & 31;
  const int n = blockIdx.x * 8 + r;
  const int b = n >> 5, p = n & 31;
  const float* Mx   = lstm ? M_s    : M_t;
  const float* bias = lstm ? bias_s : bias_t;
  const float* WhhT = lstm ? WhhT_s : WhhT_t;
  const int D = lstm ? 4 : 2;

  __shared__ float hs[8][H_];
  float c[4];
  float bb[4][4], mm[4][4][4];
  #pragma unroll
  for (int v=0;v<4;v++)
    #pragma unroll
    for (int u=0;u<4;u++){
      int g = v*H_ + 4*l + u;
      bb[v][u] = bias[g];
      #pragma unroll
      for (int d=0; d<4; ++d) mm[v][u][d] = (d<D) ? Mx[g*D + d] : 0.f;
    }
  #pragma unroll
  for (int u=0;u<4;u++){ c[u]=0.f; hs[r][4*l+u]=0.f; }

  int cnt = 0;
  for (int t=0;t<T_;t++){
    __syncthreads();                       // h writes from prev step visible
    const int m = maskI[t*N_ + n];
    cnt += (m != 0);
    float x0,x1,x2=0.f,x3=0.f;
    if (lstm==0){
      x0 = rel[(t*B_+b)*64 + p];           // (T,B,2,P) d=0
      x1 = rel[(t*B_+b)*64 + 32 + p];      // d=1
    } else {
      const int i0 = t*N_ + n;             // (T,B,1,P) flat
      x0 = pvx[i0]; x1 = pvy[i0]; x2 = pax[i0]; x3 = pay[i0];
    }
    float acc[4][4];
    #pragma unroll
    for (int v=0;v<4;v++)
      #pragma unroll
      for (int u=0;u<4;u++)
        acc[v][u] = bb[v][u] + x0*mm[v][u][0] + x1*mm[v][u][1] + x2*mm[v][u][2] + x3*mm[v][u][3];

    const float* wbase = WhhT + 4*l;
    #pragma unroll 4
    for (int k=0;k<H_;k++){
      const float hk = hs[r][k];
      const float* wrow = wbase + k*G_;
      #pragma unroll
      for (int v=0;v<4;v++){
        const float4 w = *reinterpret_cast<const float4*>(wrow + v*H_);
        acc[v][0] += hk*w.x; acc[v][1] += hk*w.y; acc[v][2] += hk*w.z; acc[v][3] += hk*w.w;
      }
    }
    __syncthreads();                       // all h reads done before overwrite
    if (m){
      #pragma unroll
      for (int u=0;u<4;u++){
        const float ig = sigm(acc[0][u]);
        const float fg = sigm(acc[1][u]);
        const float gg = tanhf(acc[2][u]);
        const float og = sigm(acc[3][u]);
        const float cn = fg*c[u] + ig*gg;
        c[u] = cn;
        hs[r][4*l+u] = og*tanhf(cn);
      }
    }
  }
  __syncthreads();
  float* hout = lstm ? h_s_out : h_t_out;
  #pragma unroll
  for (int u=0;u<4;u++) hout[n*H_ + 4*l + u] = hs[r][4*l+u];
  if (lstm==0 && l==0) okb[n] = (cnt >= 2) ? 1.f : 0.f;
}

// ---------------- Kernel 2: fused = relu(relu([h_t,h_s]@F1T+f1)@F2T+f2) * ok ----------------
__global__ __launch_bounds__(128) void fuse_kernel(
    const float* __restrict__ h_t, const float* __restrict__ h_s,
    const float* __restrict__ F1T, const float* __restrict__ f1,
    const float* __restrict__ F2T, const float* __restrict__ f2,
    const float* __restrict__ okb, float* __restrict__ fused)
{
  const int n = blockIdx.x, j = threadIdx.x;
  __shared__ float comb[2*H_];
  __shared__ float hid[H_];
  comb[j]      = h_t[n*H_+j];
  comb[H_+j]   = h_s[n*H_+j];
  __syncthreads();
  float acc = f1[j];
  for (int k=0;k<2*H_;k++) acc += comb[k]*F1T[k*H_+j];
  hid[j] = fmaxf(acc, 0.f);
  __syncthreads();
  float acc2 = f2[j];
  for (int k=0;k<H_;k++) acc2 += hid[k]*F2T[k*H_+j];
  fused[n*H_+j] = fmaxf(acc2, 0.f) * okb[n];
}

// ---------------- Kernel 3: per-batch attention pool ----------------
__global__ __launch_bounds__(128) void attn_kernel(
    const float* __restrict__ fused, const float* __restrict__ okb,
    const float* __restrict__ A1, const float* __restrict__ a1,
    const float* __restrict__ A2, const float* __restrict__ a2v,
    float* __restrict__ out)
{
  const int b = blockIdx.x, tid = threadIdx.x;
  __shared__ float fl[P_*H_];      // 16 KB
  __shared__ float mean[H_];
  __shared__ float okv[P_];
  __shared__ float partial[P_][4];
  __shared__ float sc[P_];
  __shared__ float wgt[P_];
  for (int i=tid;i<P_*H_;i+=128) fl[i] = fused[b*P_*H_ + i];
  if (tid < P_) okv[tid] = okb[b*P_ + tid];
  __syncthreads();
  {
    float s=0.f; for (int p=0;p<P_;p++) s += fl[p*H_+tid];
    float nv=0.f; for (int p=0;p<P_;p++) nv += okv[p];
    mean[tid] = s / fmaxf(nv, 1.f);
  }
  __syncthreads();
  {
    const int p = tid >> 2, ch = tid & 3;
    float part = 0.f;
    for (int j = ch*32; j < ch*32+32; ++j){
      float acc = a1[j];
      const float* arow = A1 + j*2*H_;
      for (int k=0;k<H_;k++) acc += fl[p*H_+k]*arow[k];
      for (int k=0;k<H_;k++) acc += mean[k]*arow[H_+k];
      part += fmaxf(acc, 0.f) * A2[j];
    }
    partial[p][ch] = part;
  }
  __syncthreads();
  if (tid < P_){
    float s = a2v[0] + partial[tid][0]+partial[tid][1]+partial[tid][2]+partial[tid][3];
    s = fmaxf(s, 0.f);
    sc[tid] = (okv[tid] > 0.f) ? s : -1e9f;
  }
  __syncthreads();
  if (tid == 0){
    float mx = -1e30f;
    for (int p2=0;p2<P_;p2++) mx = fmaxf(mx, sc[p2]);
    float se = 0.f;
    for (int p2=0;p2<P_;p2++){
      float ev = (okv[p2] > 0.f) ? __expf(sc[p2]-mx) : 0.f;
      wgt[p2] = ev; se += ev;
    }
    const float inv = 1.f / fmaxf(se, 1e-9f);
    for (int p2=0;p2<P_;p2++) wgt[p2] *= inv;
  }
  __syncthreads();
  {
    float acc = 0.f;
    for (int p2=0;p2<P_;p2++) acc += wgt[p2]*fl[p2*H_+tid];
    out[b*H_ + tid] = acc;
  }
}

extern "C" void kernel_launch(void* const* d_in, const int* in_sizes, int n_in,
                              void* d_out, int out_size, void* d_ws, size_t ws_size,
                              hipStream_t stream) {
  const float* rel   = (const float*)d_in[1];
  const float* pvx   = (const float*)d_in[2];
  const float* pvy   = (const float*)d_in[3];
  const float* pax   = (const float*)d_in[4];
  const float* pay   = (const float*)d_in[5];
  const int*   pmask = (const int*)  d_in[6];
  const float* W_sp  = (const float*)d_in[7];
  const float* b_sp  = (const float*)d_in[8];
  const float* W_st  = (const float*)d_in[9];
  const float* b_st  = (const float*)d_in[10];
  const float* Wih_t = (const float*)d_in[11];
  const float* Whh_t = (const float*)d_in[12];
  const float* bih_t = (const float*)d_in[13];
  const float* bhh_t = (const float*)d_in[14];
  const float* Wih_s = (const float*)d_in[15];
  const float* Whh_s = (const float*)d_in[16];
  const float* bih_s = (const float*)d_in[17];
  const float* bhh_s = (const float*)d_in[18];
  const float* A1    = (const float*)d_in[19];
  const float* a1    = (const float*)d_in[20];
  const float* A2    = (const float*)d_in[21];
  const float* a2v   = (const float*)d_in[22];
  const float* F1    = (const float*)d_in[23];
  const float* f1    = (const float*)d_in[24];
  const float* F2    = (const float*)d_in[25];
  const float* f2    = (const float*)d_in[26];

  float* ws = (float*)d_ws;
  size_t off = 0;
  float* WhhT_t = ws + off; off += (size_t)G_*H_;   // 65536
  float* WhhT_s = ws + off; off += (size_t)G_*H_;
  float* M_t    = ws + off; off += (size_t)G_*2;
  float* M_s    = ws + off; off += (size_t)G_*4;
  float* bias_t = ws + off; off += G_;
  float* bias_s = ws + off; off += G_;
  float* F1T    = ws + off; off += (size_t)2*H_*H_; // 32768
  float* F2T    = ws + off; off += (size_t)H_*H_;
  float* h_t    = ws + off; off += (size_t)N_*H_;
  float* h_s    = ws + off; off += (size_t)N_*H_;
  float* fusedb = ws + off; off += (size_t)N_*H_;
  float* okb    = ws + off; off += N_;

  hipLaunchKernelGGL(prep_kernel, dim3(4), dim3(256), 0, stream,
      W_sp, b_sp, W_st, b_st, Wih_t, Whh_t, bih_t, bhh_t,
      Wih_s, Whh_s, bih_s, bhh_s, F1, F2,
      M_t, bias_t, M_s, bias_s, WhhT_t, WhhT_s, F1T, F2T);

  hipLaunchKernelGGL(lstm_kernel, dim3(N_/8, 2), dim3(256), 0, stream,
      rel, pvx, pvy, pax, pay, pmask,
      M_t, bias_t, WhhT_t, M_s, bias_s, WhhT_s,
      h_t, h_s, okb);

  hipLaunchKernelGGL(fuse_kernel, dim3(N_), dim3(128), 0, stream,
      h_t, h_s, F1T, f1, F2T, f2, okb, fusedb);

  hipLaunchKernelGGL(attn_kernel, dim3(B_), dim3(128), 0, stream,
      fusedb, okb, A1, a1, A2, a2v, (float*)d_out);
}

// Round 2
// 1032.936 us; speedup vs baseline: 3.3719x; 3.3719x over previous
//
#include <hip/hip_runtime.h>

#define T_ 64
#define B_ 32
#define P_ 32
#define N_ 1024
#define H_ 128
#define G_ 512          // 4*H
#define CHUNK_F32 8192  // one chunk: 16 k-values x 512 gates (32 KB)
#define NBUF 3

__device__ __forceinline__ float sigm(float x){ return 1.f/(1.f+__expf(-x)); }
__device__ __forceinline__ float tanh_fast(float x){ return 1.f - 2.f/(__expf(2.f*x)+1.f); }

// async 32KB chunk copy global->LDS, linear layout, 4 x 16B per thread (512 threads)
__device__ __forceinline__ void stage_chunk(const float* __restrict__ src, float* dst, int tid){
  #pragma unroll
  for (int i=0;i<4;i++){
    const int off = i*8192 + tid*16;   // bytes
    __builtin_amdgcn_global_load_lds(
        (const __attribute__((address_space(1))) void*)((const char*)src + off),
        (__attribute__((address_space(3))) void*)((char*)dst + off), 16, 0, 0);
  }
}

// ---------------- Kernel 0: fold input projections, build staged weight layout ----------------
// Wstg layout (per LSTM): [chunk c 0..7][k4 0..3][g 0..511][j 0..3] f32, value = Whh[g][c*16+k4*4+j]
__global__ __launch_bounds__(256) void prep_kernel(
    const float* __restrict__ W_sp, const float* __restrict__ b_sp,
    const float* __restrict__ W_st, const float* __restrict__ b_st,
    const float* __restrict__ Wih_t, const float* __restrict__ Whh_t,
    const float* __restrict__ bih_t, const float* __restrict__ bhh_t,
    const float* __restrict__ Wih_s, const float* __restrict__ Whh_s,
    const float* __restrict__ bih_s, const float* __restrict__ bhh_s,
    const float* __restrict__ F1, const float* __restrict__ F2,
    float* __restrict__ M4_t, float* __restrict__ bias_t,
    float* __restrict__ M4_s, float* __restrict__ bias_s,
    float* __restrict__ Wstg_t, float* __restrict__ Wstg_s,
    float* __restrict__ F1T, float* __restrict__ F2T)
{
  const int tid = threadIdx.x;
  const int blk = blockIdx.x;
  if (blk == 0) {
    for (int g = tid; g < G_; g += 256) {
      float m0=0.f,m1=0.f,bt=0.f;
      for (int e=0;e<H_;e++){ float w=Wih_t[g*H_+e]; m0+=w*W_sp[e*2]; m1+=w*W_sp[e*2+1]; bt+=w*b_sp[e]; }
      M4_t[g*4+0]=m0; M4_t[g*4+1]=m1; M4_t[g*4+2]=0.f; M4_t[g*4+3]=0.f;
      bias_t[g]=bt+bih_t[g]+bhh_t[g];
      float s0=0.f,s1=0.f,s2=0.f,s3=0.f,bs=0.f;
      for (int e=0;e<H_;e++){ float w=Wih_s[g*H_+e]; s0+=w*W_st[e*4]; s1+=w*W_st[e*4+1]; s2+=w*W_st[e*4+2]; s3+=w*W_st[e*4+3]; bs+=w*b_st[e]; }
      M4_s[g*4+0]=s0; M4_s[g*4+1]=s1; M4_s[g*4+2]=s2; M4_s[g*4+3]=s3;
      bias_s[g]=bs+bih_s[g]+bhh_s[g];
    }
  } else if (blk == 1 || blk == 2) {
    const float* Whh = (blk==1) ? Whh_t : Whh_s;
    float* Wstg      = (blk==1) ? Wstg_t : Wstg_s;
    for (int out = tid; out < G_*H_; out += 256) {
      const int c  = out >> 13;
      const int k4 = (out >> 11) & 3;
      const int g  = (out >> 2) & 511;
      const int j  = out & 3;
      const int k  = c*16 + k4*4 + j;
      Wstg[out] = Whh[g*H_ + k];
    }
  } else if (blk == 3) {
    for (int idx = tid; idx < H_*2*H_; idx += 256) { // F1 (128,256)
      int j = idx >> 8, k = idx & 255;
      F1T[k*H_+j] = F1[idx];
    }
  } else {
    for (int idx = tid; idx < H_*H_; idx += 256) {  // F2 (128,128)
      int j = idx >> 7, k = idx & 127;
      F2T[k*H_+j] = F2[idx];
    }
  }
}

// ---------------- Kernel 1: both masked LSTMs ----------------
// grid (128, 2): x = 8-row chunk, y = lstm. 512 threads = 8 waves, 1 block/CU.
// thread tid owns gate-row g=tid for all 8 rows; activation: thread owns
// (row ar=tid>>6, units au..au+1) with c kept in registers.
// Weights stream L2->LDS via global_load_lds, 3-buffer ring, counted vmcnt(4),
// raw s_barrier (prefetch survives the barrier; __syncthreads would drain it).
__global__ __launch_bounds__(512, 1) void lstm_kernel(
    const float* __restrict__ rel, const float* __restrict__ pvx,
    const float* __restrict__ pvy, const float* __restrict__ pax,
    const float* __restrict__ pay, const int* __restrict__ maskI,
    const float* __restrict__ M4_t, const float* __restrict__ bias_t, const float* __restrict__ Wstg_t,
    const float* __restrict__ M4_s, const float* __restrict__ bias_s, const float* __restrict__ Wstg_s,
    float* __restrict__ h_t_out, float* __restrict__ h_s_out, float* __restrict__ okb)
{
  extern __shared__ float smem[];
  float* wlds = smem;                    // 3 * 8192 f32 = 96 KB
  float* hl   = smem + NBUF*CHUNK_F32;   // 8 rows x 128 = 4 KB
  const int lstm = blockIdx.y;
  const int tid  = threadIdx.x;
  const int g    = tid;
  const int n0   = blockIdx.x * 8;

  const float* Mx   = lstm ? M4_s   : M4_t;
  const float* bias = lstm ? bias_s : bias_t;
  const float* Wstg = lstm ? Wstg_s : Wstg_t;

  const float  bb = bias[g];
  const float4 mv = *(const float4*)(Mx + g*4);

  // zero h, c
  hl[tid] = 0.f; hl[tid+512] = 0.f;
  float c0 = 0.f, c1 = 0.f;
  const int ar = tid >> 6;
  const int au = (tid & 63) * 2;

  int cnt[8];
  #pragma unroll
  for (int r=0;r<8;r++) cnt[r]=0;

  // prologue: stage chunks 0,1
  stage_chunk(Wstg + 0*CHUNK_F32, wlds + 0*CHUNK_F32, tid);
  stage_chunk(Wstg + 1*CHUNK_F32, wlds + 1*CHUNK_F32, tid);

  int gc = 0;
  for (int t=0; t<T_; ++t){
    // wave-uniform x and mask (compiler: s_load); no threadIdx in addresses
    float xs[8][4];
    int mbits = 0;
    if (lstm==0){
      #pragma unroll
      for (int r=0;r<8;r++){
        const int n=n0+r, b=n>>5, p=n&31;
        xs[r][0]=rel[(t*B_+b)*64+p]; xs[r][1]=rel[(t*B_+b)*64+32+p];
        xs[r][2]=0.f; xs[r][3]=0.f;
      }
    } else {
      #pragma unroll
      for (int r=0;r<8;r++){
        const int i0=t*N_+n0+r;
        xs[r][0]=pvx[i0]; xs[r][1]=pvy[i0]; xs[r][2]=pax[i0]; xs[r][3]=pay[i0];
      }
    }
    #pragma unroll
    for (int r=0;r<8;r++){
      const int m = (maskI[t*N_+n0+r]!=0);
      mbits |= m<<r; cnt[r] += m;
    }

    float acc[8];
    #pragma unroll
    for (int r=0;r<8;r++)
      acc[r] = bb + mv.x*xs[r][0] + mv.y*xs[r][1] + mv.z*xs[r][2] + mv.w*xs[r][3];

    #pragma unroll
    for (int c=0;c<8;c++){
      // wait current chunk landed (4 newest = next chunk's loads still in flight)
      asm volatile("s_waitcnt vmcnt(4)" ::: "memory");
      asm volatile("s_waitcnt lgkmcnt(0)" ::: "memory");
      __builtin_amdgcn_s_barrier();
      asm volatile("" ::: "memory");
      // prefetch chunk gc+2 (same weights every step: source cycles mod 8)
      const int nf = gc + 2;
      stage_chunk(Wstg + (nf&7)*CHUNK_F32, wlds + (nf%3)*CHUNK_F32, tid);

      const float* wb = wlds + (gc%3)*CHUNK_F32;
      const int kb = c*16;
      #pragma unroll
      for (int k4=0;k4<4;k4++){
        const float4 w = *(const float4*)(wb + k4*2048 + g*4);      // lane-consecutive 16B
        #pragma unroll
        for (int r=0;r<8;r++){
          const float4 hv = *(const float4*)(hl + r*128 + kb + k4*4); // broadcast
          acc[r] += w.x*hv.x + w.y*hv.y + w.z*hv.z + w.w*hv.w;
        }
      }
      gc++;
    }

    // gates -> the just-freed ring buffer (chunk (gc-1)%3; in-flight stages target the other two)
    float* gbuf = wlds + ((gc-1)%3)*CHUNK_F32;
    #pragma unroll
    for (int r=0;r<8;r++) gbuf[r*G_ + g] = acc[r];
    asm volatile("s_waitcnt lgkmcnt(0)" ::: "memory");
    __builtin_amdgcn_s_barrier();
    asm volatile("" ::: "memory");

    // activation: thread owns (ar, au..au+1)
    if ((mbits>>ar)&1){
      const float2 gi = *(const float2*)(gbuf + ar*G_ +   0 + au);
      const float2 gf = *(const float2*)(gbuf + ar*G_ + 128 + au);
      const float2 gg = *(const float2*)(gbuf + ar*G_ + 256 + au);
      const float2 go = *(const float2*)(gbuf + ar*G_ + 384 + au);
      c0 = sigm(gf.x)*c0 + sigm(gi.x)*tanh_fast(gg.x);
      c1 = sigm(gf.y)*c1 + sigm(gi.y)*tanh_fast(gg.y);
      float2 hh; hh.x = sigm(go.x)*tanh_fast(c0); hh.y = sigm(go.y)*tanh_fast(c1);
      *(float2*)(hl + ar*H_ + au) = hh;
    }
    // next iteration's chunk-0 barrier makes h visible before reads
  }

  // output: thread's own pair (only ever written by this thread)
  float* hout = lstm ? h_s_out : h_t_out;
  const float2 hv = *(const float2*)(hl + ar*H_ + au);
  *(float2*)(hout + (n0+ar)*H_ + au) = hv;
  if (lstm==0){
    #pragma unroll
    for (int r=0;r<8;r++) if (tid == r*64) okb[n0+r] = (cnt[r] >= 2) ? 1.f : 0.f;
  }
}

// ---------------- Kernel 2: fused = relu(relu([h_t,h_s]@F1T+f1)@F2T+f2) * ok ----------------
__global__ __launch_bounds__(128) void fuse_kernel(
    const float* __restrict__ h_t, const float* __restrict__ h_s,
    const float* __restrict__ F1T, const float* __restrict__ f1,
    const float* __restrict__ F2T, const float* __restrict__ f2,
    const float* __restrict__ okb, float* __restrict__ fused)
{
  const int n = blockIdx.x, j = threadIdx.x;
  __shared__ float comb[2*H_];
  __shared__ float hid[H_];
  comb[j]      = h_t[n*H_+j];
  comb[H_+j]   = h_s[n*H_+j];
  __syncthreads();
  float acc = f1[j];
  for (int k=0;k<2*H_;k++) acc += comb[k]*F1T[k*H_+j];
  hid[j] = fmaxf(acc, 0.f);
  __syncthreads();
  float acc2 = f2[j];
  for (int k=0;k<H_;k++) acc2 += hid[k]*F2T[k*H_+j];
  fused[n*H_+j] = fmaxf(acc2, 0.f) * okb[n];
}

// ---------------- Kernel 3: per-batch attention pool ----------------
__global__ __launch_bounds__(128) void attn_kernel(
    const float* __restrict__ fused, const float* __restrict__ okb,
    const float* __restrict__ A1, const float* __restrict__ a1,
    const float* __restrict__ A2, const float* __restrict__ a2v,
    float* __restrict__ out)
{
  const int b = blockIdx.x, tid = threadIdx.x;
  __shared__ float fl[P_*H_];      // 16 KB
  __shared__ float mean[H_];
  __shared__ float okv[P_];
  __shared__ float partial[P_][4];
  __shared__ float sc[P_];
  __shared__ float wgt[P_];
  for (int i=tid;i<P_*H_;i+=128) fl[i] = fused[b*P_*H_ + i];
  if (tid < P_) okv[tid] = okb[b*P_ + tid];
  __syncthreads();
  {
    float s=0.f; for (int p=0;p<P_;p++) s += fl[p*H_+tid];
    float nv=0.f; for (int p=0;p<P_;p++) nv += okv[p];
    mean[tid] = s / fmaxf(nv, 1.f);
  }
  __syncthreads();
  {
    const int p = tid >> 2, ch = tid & 3;
    float part = 0.f;
    for (int j = ch*32; j < ch*32+32; ++j){
      float acc = a1[j];
      const float* arow = A1 + j*2*H_;
      for (int k=0;k<H_;k++) acc += fl[p*H_+k]*arow[k];
      for (int k=0;k<H_;k++) acc += mean[k]*arow[H_+k];
      part += fmaxf(acc, 0.f) * A2[j];
    }
    partial[p][ch] = part;
  }
  __syncthreads();
  if (tid < P_){
    float s = a2v[0] + partial[tid][0]+partial[tid][1]+partial[tid][2]+partial[tid][3];
    s = fmaxf(s, 0.f);
    sc[tid] = (okv[tid] > 0.f) ? s : -1e9f;
  }
  __syncthreads();
  if (tid == 0){
    float mx = -1e30f;
    for (int p2=0;p2<P_;p2++) mx = fmaxf(mx, sc[p2]);
    float se = 0.f;
    for (int p2=0;p2<P_;p2++){
      float ev = (okv[p2] > 0.f) ? __expf(sc[p2]-mx) : 0.f;
      wgt[p2] = ev; se += ev;
    }
    const float inv = 1.f / fmaxf(se, 1e-9f);
    for (int p2=0;p2<P_;p2++) wgt[p2] *= inv;
  }
  __syncthreads();
  {
    float acc = 0.f;
    for (int p2=0;p2<P_;p2++) acc += wgt[p2]*fl[p2*H_+tid];
    out[b*H_ + tid] = acc;
  }
}

extern "C" void kernel_launch(void* const* d_in, const int* in_sizes, int n_in,
                              void* d_out, int out_size, void* d_ws, size_t ws_size,
                              hipStream_t stream) {
  const float* rel   = (const float*)d_in[1];
  const float* pvx   = (const float*)d_in[2];
  const float* pvy   = (const float*)d_in[3];
  const float* pax   = (const float*)d_in[4];
  const float* pay   = (const float*)d_in[5];
  const int*   pmask = (const int*)  d_in[6];
  const float* W_sp  = (const float*)d_in[7];
  const float* b_sp  = (const float*)d_in[8];
  const float* W_st  = (const float*)d_in[9];
  const float* b_st  = (const float*)d_in[10];
  const float* Wih_t = (const float*)d_in[11];
  const float* Whh_t = (const float*)d_in[12];
  const float* bih_t = (const float*)d_in[13];
  const float* bhh_t = (const float*)d_in[14];
  const float* Wih_s = (const float*)d_in[15];
  const float* Whh_s = (const float*)d_in[16];
  const float* bih_s = (const float*)d_in[17];
  const float* bhh_s = (const float*)d_in[18];
  const float* A1    = (const float*)d_in[19];
  const float* a1    = (const float*)d_in[20];
  const float* A2    = (const float*)d_in[21];
  const float* a2v   = (const float*)d_in[22];
  const float* F1    = (const float*)d_in[23];
  const float* f1    = (const float*)d_in[24];
  const float* F2    = (const float*)d_in[25];
  const float* f2    = (const float*)d_in[26];

  float* ws = (float*)d_ws;
  size_t off = 0;
  float* Wstg_t = ws + off; off += (size_t)G_*H_;   // 65536
  float* Wstg_s = ws + off; off += (size_t)G_*H_;
  float* M4_t   = ws + off; off += (size_t)G_*4;
  float* M4_s   = ws + off; off += (size_t)G_*4;
  float* bias_t = ws + off; off += G_;
  float* bias_s = ws + off; off += G_;
  float* F1T    = ws + off; off += (size_t)2*H_*H_; // 32768
  float* F2T    = ws + off; off += (size_t)H_*H_;
  float* h_t    = ws + off; off += (size_t)N_*H_;
  float* h_s    = ws + off; off += (size_t)N_*H_;
  float* fusedb = ws + off; off += (size_t)N_*H_;
  float* okb    = ws + off; off += N_;

  hipLaunchKernelGGL(prep_kernel, dim3(5), dim3(256), 0, stream,
      W_sp, b_sp, W_st, b_st, Wih_t, Whh_t, bih_t, bhh_t,
      Wih_s, Whh_s, bih_s, bhh_s, F1, F2,
      M4_t, bias_t, M4_s, bias_s, Wstg_t, Wstg_s, F1T, F2T);

  const int lstm_lds = (NBUF*CHUNK_F32 + 8*H_) * 4;  // 102400 B
  hipFuncSetAttribute((const void*)lstm_kernel,
                      hipFuncAttributeMaxDynamicSharedMemorySize, lstm_lds);
  hipLaunchKernelGGL(lstm_kernel, dim3(N_/8, 2), dim3(512), lstm_lds, stream,
      rel, pvx, pvy, pax, pay, pmask,
      M4_t, bias_t, Wstg_t, M4_s, bias_s, Wstg_s,
      h_t, h_s, okb);

  hipLaunchKernelGGL(fuse_kernel, dim3(N_), dim3(128), 0, stream,
      h_t, h_s, F1T, f1, F2T, f2, okb, fusedb);

  hipLaunchKernelGGL(attn_kernel, dim3(B_), dim3(128), 0, stream,
      fusedb, okb, A1, a1, A2, a2v, (float*)d_out);
}

// Round 3
// 305.153 us; speedup vs baseline: 11.4138x; 3.3850x over previous
//
#include <hip/hip_runtime.h>

#define T_ 64
#define B_ 32
#define P_ 32
#define N_ 1024
#define H_ 128
#define G_ 512   // 4*H

typedef __attribute__((ext_vector_type(8))) _Float16 half8;
typedef __attribute__((ext_vector_type(4))) float f32x4;

__device__ __forceinline__ float sigm(float x){ return 1.f/(1.f+__expf(-x)); }
__device__ __forceinline__ float tanh_fast(float x){ return 1.f - 2.f/(__expf(2.f*x)+1.f); }

// ---------------- Kernel 0: prep ----------------
// blk 0: fold input projections -> M4 (G,4) + bias (G)
// blk 1-8: W fragments, f16, MFMA B-layout: [L][w][n][t][lane][j]
//          g = n*128 + w*16 + (lane&15), k = t*32 + 8*(lane>>4) + j
// blk 9: F1T, blk 10: F2T, blk 11-14: okb
__global__ __launch_bounds__(256) void prep_kernel(
    const float* __restrict__ W_sp, const float* __restrict__ b_sp,
    const float* __restrict__ W_st, const float* __restrict__ b_st,
    const float* __restrict__ Wih_t, const float* __restrict__ Whh_t,
    const float* __restrict__ bih_t, const float* __restrict__ bhh_t,
    const float* __restrict__ Wih_s, const float* __restrict__ Whh_s,
    const float* __restrict__ bih_s, const float* __restrict__ bhh_s,
    const float* __restrict__ F1, const float* __restrict__ F2,
    const int* __restrict__ maskI,
    float* __restrict__ M4_t, float* __restrict__ bias_t,
    float* __restrict__ M4_s, float* __restrict__ bias_s,
    _Float16* __restrict__ Wfrag,
    float* __restrict__ F1T, float* __restrict__ F2T,
    float* __restrict__ okb)
{
  const int tid = threadIdx.x;
  const int blk = blockIdx.x;
  if (blk == 0) {
    for (int g = tid; g < G_; g += 256) {
      float m0=0.f,m1=0.f,bt=0.f;
      for (int e=0;e<H_;e++){ float w=Wih_t[g*H_+e]; m0+=w*W_sp[e*2]; m1+=w*W_sp[e*2+1]; bt+=w*b_sp[e]; }
      M4_t[g*4+0]=m0; M4_t[g*4+1]=m1; M4_t[g*4+2]=0.f; M4_t[g*4+3]=0.f;
      bias_t[g]=bt+bih_t[g]+bhh_t[g];
      float s0=0.f,s1=0.f,s2=0.f,s3=0.f,bs=0.f;
      for (int e=0;e<H_;e++){ float w=Wih_s[g*H_+e]; s0+=w*W_st[e*4]; s1+=w*W_st[e*4+1]; s2+=w*W_st[e*4+2]; s3+=w*W_st[e*4+3]; bs+=w*b_st[e]; }
      M4_s[g*4+0]=s0; M4_s[g*4+1]=s1; M4_s[g*4+2]=s2; M4_s[g*4+3]=s3;
      bias_s[g]=bs+bih_s[g]+bhh_s[g];
    }
  } else if (blk <= 8) {
    const int L = (blk-1) >> 2;           // lstm
    const int q = (blk-1) & 3;            // quarter
    const float* Whh = L ? Whh_s : Whh_t;
    for (int e = q*16384 + tid; e < (q+1)*16384; e += 256) {
      const int j  = e & 7;
      const int l  = (e >> 3) & 63;
      const int t  = (e >> 9) & 3;
      const int n  = (e >> 11) & 3;
      const int w  = (e >> 13) & 7;
      const int g  = n*128 + w*16 + (l & 15);
      const int k  = t*32 + 8*(l >> 4) + j;
      Wfrag[L*65536 + e] = (_Float16)Whh[g*H_ + k];
    }
  } else if (blk == 9) {
    for (int idx = tid; idx < H_*2*H_; idx += 256) { // F1 (128,256)
      int j = idx >> 8, k = idx & 255;
      F1T[k*H_+j] = F1[idx];
    }
  } else if (blk == 10) {
    for (int idx = tid; idx < H_*H_; idx += 256) {  // F2 (128,128)
      int j = idx >> 7, k = idx & 127;
      F2T[k*H_+j] = F2[idx];
    }
  } else {
    const int n = (blk-11)*256 + tid;
    int cnt = 0;
    for (int t=0;t<T_;t++) cnt += (maskI[t*N_ + n] > 0);
    okb[n] = (cnt >= 2) ? 1.f : 0.f;
  }
}

// ---------------- Kernel 1: both masked LSTMs, MFMA, weights in VGPRs ----------------
// grid (128, 2): x = 8-row chunk, y = lstm. 512 threads = 8 waves.
// wave w owns units u = w*16 + (lane&15); ntile n = gate type n (i,f,g,o) at
// gates n*128+u. Lane holds C rows r0..r0+3 (r0=(lane>>4)*4; rows 8-15 pad).
// h kept in LDS as f16 hi+lo in A-fragment layout, double-buffered; activation
// fully in-register (C layout: col=lane&15, row=(lane>>4)*4+reg).
__global__ __launch_bounds__(512, 2) void lstm_kernel(
    const float* __restrict__ rel, const float* __restrict__ pvx,
    const float* __restrict__ pvy, const float* __restrict__ pax,
    const float* __restrict__ pay, const int* __restrict__ maskI,
    const float* __restrict__ M4_t, const float* __restrict__ bias_t,
    const float* __restrict__ M4_s, const float* __restrict__ bias_s,
    const _Float16* __restrict__ Wfrag,
    float* __restrict__ h_t_out, float* __restrict__ h_s_out)
{
  __shared__ _Float16 hA[2][2][4][64][8] __align__(16);  // [buf][hi/lo][ktile][lane][j] 16KB
  __shared__ float4 xsh[T_][8];                          // x per (t, row) 8KB
  __shared__ unsigned int ml[T_];                        // mask bits per t

  const int lstm = blockIdx.y;
  const int tid  = threadIdx.x;
  const int w    = tid >> 6;
  const int l    = tid & 63;
  const int n0   = blockIdx.x * 8;
  const int u    = w*16 + (l & 15);      // unit this lane owns for activation
  const int kt_u = u >> 5;
  const int r0   = (l >> 4) * 4;

  const float* M4   = lstm ? M4_s   : M4_t;
  const float* bias = lstm ? bias_s : bias_t;

  // ---- load B fragments (weights) into VGPRs: 4 ntile x 4 ktile x half8 ----
  half8 bw[4][4];
  #pragma unroll
  for (int n=0;n<4;n++)
    #pragma unroll
    for (int t=0;t<4;t++){
      const int base = ((((lstm*8 + w)*4 + n)*4 + t)*64 + l)*8;
      bw[n][t] = *(const half8*)(Wfrag + base);
    }

  // per-gate bias and input-projection rows for this lane's 4 gate-types
  float bb[4]; float4 mvn[4];
  #pragma unroll
  for (int n=0;n<4;n++){
    const int g = n*128 + u;
    bb[n]  = bias[g];
    mvn[n] = *(const float4*)(M4 + g*4);
  }

  // ---- stage x and mask into LDS ----
  {
    const int t = tid >> 3, r = tid & 7;
    const int n = n0 + r, b = n >> 5, p = n & 31;
    float4 xv;
    if (lstm == 0){
      xv.x = rel[(t*B_+b)*64 + p];
      xv.y = rel[(t*B_+b)*64 + 32 + p];
      xv.z = 0.f; xv.w = 0.f;
    } else {
      const int i0 = t*N_ + n;
      xv.x = pvx[i0]; xv.y = pvy[i0]; xv.z = pax[i0]; xv.w = pay[i0];
    }
    xsh[t][r] = xv;
    if (tid < T_){
      unsigned int mw = 0;
      for (int rr=0; rr<8; rr++) mw |= (maskI[tid*N_ + n0 + rr] > 0) ? (1u<<rr) : 0u;
      ml[tid] = mw;
    }
  }
  // zero both h buffers (8192 halves = 4096 u32)
  {
    unsigned int* hz = (unsigned int*)&hA[0][0][0][0][0];
    #pragma unroll
    for (int i=0;i<8;i++) hz[tid + i*512] = 0u;
  }
  float c0=0.f,c1=0.f,c2=0.f,c3=0.f;
  __syncthreads();

  for (int t=0; t<T_; ++t){
    const int cur = t & 1, nxt = cur ^ 1;
    const unsigned int mw = ml[t];

    // x for this lane's 4 rows (rows>=8 read clamped; results unused)
    float4 xv0 = xsh[t][(r0+0)&7];
    float4 xv1 = xsh[t][(r0+1)&7];
    float4 xv2 = xsh[t][(r0+2)&7];
    float4 xv3 = xsh[t][(r0+3)&7];

    f32x4 acc[4];
    #pragma unroll
    for (int n=0;n<4;n++){
      acc[n][0] = bb[n] + mvn[n].x*xv0.x + mvn[n].y*xv0.y + mvn[n].z*xv0.z + mvn[n].w*xv0.w;
      acc[n][1] = bb[n] + mvn[n].x*xv1.x + mvn[n].y*xv1.y + mvn[n].z*xv1.z + mvn[n].w*xv1.w;
      acc[n][2] = bb[n] + mvn[n].x*xv2.x + mvn[n].y*xv2.y + mvn[n].z*xv2.z + mvn[n].w*xv2.w;
      acc[n][3] = bb[n] + mvn[n].x*xv3.x + mvn[n].y*xv3.y + mvn[n].z*xv3.z + mvn[n].w*xv3.w;
    }

    // A fragments: h hi/lo
    half8 ah[4], al[4];
    #pragma unroll
    for (int kt=0;kt<4;kt++){
      ah[kt] = *(const half8*)&hA[cur][0][kt][l][0];
      al[kt] = *(const half8*)&hA[cur][1][kt][l][0];
    }

    #pragma unroll
    for (int n=0;n<4;n++)
      #pragma unroll
      for (int kt=0;kt<4;kt++){
        acc[n] = __builtin_amdgcn_mfma_f32_16x16x32_f16(ah[kt], bw[n][kt], acc[n], 0, 0, 0);
        acc[n] = __builtin_amdgcn_mfma_f32_16x16x32_f16(al[kt], bw[n][kt], acc[n], 0, 0, 0);
      }

    // in-register activation; lane owns (rows r0..r0+3, unit u)
    float cc[4] = {c0,c1,c2,c3};
    #pragma unroll
    for (int i=0;i<4;i++){
      const int row = r0 + i;
      const float ig = acc[0][i], fg = acc[1][i], gv = acc[2][i], og = acc[3][i];
      const float cn = sigm(fg)*cc[i] + sigm(ig)*tanh_fast(gv);
      const float hn = sigm(og)*tanh_fast(cn);
      const int mb = (mw >> (row & 7)) & 1;
      if (mb) cc[i] = cn;
      const _Float16 nh = (_Float16)hn;
      const _Float16 nl = (_Float16)(hn - (float)nh);
      const int lpp = (row & 15) + 16*((u >> 3) & 3);
      const int jj = u & 7;
      const _Float16 oh = hA[cur][0][kt_u][lpp][jj];
      const _Float16 ol = hA[cur][1][kt_u][lpp][jj];
      hA[nxt][0][kt_u][lpp][jj] = mb ? nh : oh;
      hA[nxt][1][kt_u][lpp][jj] = mb ? nl : ol;
    }
    c0=cc[0]; c1=cc[1]; c2=cc[2]; c3=cc[3];
    __syncthreads();
  }

  // final h lives in buffer 0 (t=63 wrote nxt=0)
  float* hout = lstm ? h_s_out : h_t_out;
  if (l < 32){
    #pragma unroll
    for (int i=0;i<4;i++){
      const int row = r0 + i;                // 0..7
      const int lpp = row + 16*((u >> 3) & 3);
      const int jj = u & 7;
      const float hv = (float)hA[0][0][kt_u][lpp][jj] + (float)hA[0][1][kt_u][lpp][jj];
      hout[(n0+row)*H_ + u] = hv;
    }
  }
}

// ---------------- Kernel 2: fused = relu(relu([h_t,h_s]@F1T+f1)@F2T+f2) * ok ----------------
__global__ __launch_bounds__(128) void fuse_kernel(
    const float* __restrict__ h_t, const float* __restrict__ h_s,
    const float* __restrict__ F1T, const float* __restrict__ f1,
    const float* __restrict__ F2T, const float* __restrict__ f2,
    const float* __restrict__ okb, float* __restrict__ fused)
{
  const int n = blockIdx.x, j = threadIdx.x;
  __shared__ float comb[2*H_];
  __shared__ float hid[H_];
  comb[j]      = h_t[n*H_+j];
  comb[H_+j]   = h_s[n*H_+j];
  __syncthreads();
  float acc = f1[j];
  for (int k=0;k<2*H_;k++) acc += comb[k]*F1T[k*H_+j];
  hid[j] = fmaxf(acc, 0.f);
  __syncthreads();
  float acc2 = f2[j];
  for (int k=0;k<H_;k++) acc2 += hid[k]*F2T[k*H_+j];
  fused[n*H_+j] = fmaxf(acc2, 0.f) * okb[n];
}

// ---------------- Kernel 3: per-batch attention pool ----------------
__global__ __launch_bounds__(128) void attn_kernel(
    const float* __restrict__ fused, const float* __restrict__ okb,
    const float* __restrict__ A1, const float* __restrict__ a1,
    const float* __restrict__ A2, const float* __restrict__ a2v,
    float* __restrict__ out)
{
  const int b = blockIdx.x, tid = threadIdx.x;
  __shared__ float fl[P_*H_];      // 16 KB
  __shared__ float mean[H_];
  __shared__ float okv[P_];
  __shared__ float partial[P_][4];
  __shared__ float sc[P_];
  __shared__ float wgt[P_];
  for (int i=tid;i<P_*H_;i+=128) fl[i] = fused[b*P_*H_ + i];
  if (tid < P_) okv[tid] = okb[b*P_ + tid];
  __syncthreads();
  {
    float s=0.f; for (int p=0;p<P_;p++) s += fl[p*H_+tid];
    float nv=0.f; for (int p=0;p<P_;p++) nv += okv[p];
    mean[tid] = s / fmaxf(nv, 1.f);
  }
  __syncthreads();
  {
    const int p = tid >> 2, ch = tid & 3;
    float part = 0.f;
    for (int j = ch*32; j < ch*32+32; ++j){
      float acc = a1[j];
      const float* arow = A1 + j*2*H_;
      for (int k=0;k<H_;k++) acc += fl[p*H_+k]*arow[k];
      for (int k=0;k<H_;k++) acc += mean[k]*arow[H_+k];
      part += fmaxf(acc, 0.f) * A2[j];
    }
    partial[p][ch] = part;
  }
  __syncthreads();
  if (tid < P_){
    float s = a2v[0] + partial[tid][0]+partial[tid][1]+partial[tid][2]+partial[tid][3];
    s = fmaxf(s, 0.f);
    sc[tid] = (okv[tid] > 0.f) ? s : -1e9f;
  }
  __syncthreads();
  if (tid == 0){
    float mx = -1e30f;
    for (int p2=0;p2<P_;p2++) mx = fmaxf(mx, sc[p2]);
    float se = 0.f;
    for (int p2=0;p2<P_;p2++){
      float ev = (okv[p2] > 0.f) ? __expf(sc[p2]-mx) : 0.f;
      wgt[p2] = ev; se += ev;
    }
    const float inv = 1.f / fmaxf(se, 1e-9f);
    for (int p2=0;p2<P_;p2++) wgt[p2] *= inv;
  }
  __syncthreads();
  {
    float acc = 0.f;
    for (int p2=0;p2<P_;p2++) acc += wgt[p2]*fl[p2*H_+tid];
    out[b*H_ + tid] = acc;
  }
}

extern "C" void kernel_launch(void* const* d_in, const int* in_sizes, int n_in,
                              void* d_out, int out_size, void* d_ws, size_t ws_size,
                              hipStream_t stream) {
  const float* rel   = (const float*)d_in[1];
  const float* pvx   = (const float*)d_in[2];
  const float* pvy   = (const float*)d_in[3];
  const float* pax   = (const float*)d_in[4];
  const float* pay   = (const float*)d_in[5];
  const int*   pmask = (const int*)  d_in[6];
  const float* W_sp  = (const float*)d_in[7];
  const float* b_sp  = (const float*)d_in[8];
  const float* W_st  = (const float*)d_in[9];
  const float* b_st  = (const float*)d_in[10];
  const float* Wih_t = (const float*)d_in[11];
  const float* Whh_t = (const float*)d_in[12];
  const float* bih_t = (const float*)d_in[13];
  const float* bhh_t = (const float*)d_in[14];
  const float* Wih_s = (const float*)d_in[15];
  const float* Whh_s = (const float*)d_in[16];
  const float* bih_s = (const float*)d_in[17];
  const float* bhh_s = (const float*)d_in[18];
  const float* A1    = (const float*)d_in[19];
  const float* a1    = (const float*)d_in[20];
  const float* A2    = (const float*)d_in[21];
  const float* a2v   = (const float*)d_in[22];
  const float* F1    = (const float*)d_in[23];
  const float* f1    = (const float*)d_in[24];
  const float* F2    = (const float*)d_in[25];
  const float* f2    = (const float*)d_in[26];

  float* ws = (float*)d_ws;
  size_t off = 0;
  _Float16* Wfrag = (_Float16*)(ws + off); off += 65536;   // 131072 f16 = 64K floats
  float* M4_t   = ws + off; off += (size_t)G_*4;
  float* M4_s   = ws + off; off += (size_t)G_*4;
  float* bias_t = ws + off; off += G_;
  float* bias_s = ws + off; off += G_;
  float* F1T    = ws + off; off += (size_t)2*H_*H_;
  float* F2T    = ws + off; off += (size_t)H_*H_;
  float* h_t    = ws + off; off += (size_t)N_*H_;
  float* h_s    = ws + off; off += (size_t)N_*H_;
  float* fusedb = ws + off; off += (size_t)N_*H_;
  float* okb    = ws + off; off += N_;

  hipLaunchKernelGGL(prep_kernel, dim3(15), dim3(256), 0, stream,
      W_sp, b_sp, W_st, b_st, Wih_t, Whh_t, bih_t, bhh_t,
      Wih_s, Whh_s, bih_s, bhh_s, F1, F2, pmask,
      M4_t, bias_t, M4_s, bias_s, Wfrag, F1T, F2T, okb);

  hipLaunchKernelGGL(lstm_kernel, dim3(N_/8, 2), dim3(512), 0, stream,
      rel, pvx, pvy, pax, pay, pmask,
      M4_t, bias_t, M4_s, bias_s, Wfrag,
      h_t, h_s);

  hipLaunchKernelGGL(fuse_kernel, dim3(N_), dim3(128), 0, stream,
      h_t, h_s, F1T, f1, F2T, f2, okb, fusedb);

  hipLaunchKernelGGL(attn_kernel, dim3(B_), dim3(128), 0, stream,
      fusedb, okb, A1, a1, A2, a2v, (float*)d_out);
}

// Round 4
// 197.983 us; speedup vs baseline: 17.5921x; 1.5413x over previous
//
#include <hip/hip_runtime.h>

#define T_ 64
#define B_ 32
#define P_ 32
#define N_ 1024
#define H_ 128
#define G_ 512   // 4*H

typedef __attribute__((ext_vector_type(8))) _Float16 half8;
typedef __attribute__((ext_vector_type(4))) float f32x4;

__device__ __forceinline__ float sigm(float x){ return 1.f/(1.f+__expf(-x)); }
__device__ __forceinline__ float tanh_fast(float x){ return 1.f - 2.f/(__expf(2.f*x)+1.f); }

// ---------------- Kernel 0: prep ----------------
// blk 0: fold input projections -> M4 (G,4) + bias (G)
// blk 1-8: W fragments, f16, MFMA B-layout: [L][w][n][t][lane][j]
//          g = n*128 + w*16 + (lane&15), k = t*32 + 8*(lane>>4) + j
// blk 9: F1T, blk 10: F2T, blk 11-14: okb, blk 15: A1T
__global__ __launch_bounds__(256) void prep_kernel(
    const float* __restrict__ W_sp, const float* __restrict__ b_sp,
    const float* __restrict__ W_st, const float* __restrict__ b_st,
    const float* __restrict__ Wih_t, const float* __restrict__ Whh_t,
    const float* __restrict__ bih_t, const float* __restrict__ bhh_t,
    const float* __restrict__ Wih_s, const float* __restrict__ Whh_s,
    const float* __restrict__ bih_s, const float* __restrict__ bhh_s,
    const float* __restrict__ F1, const float* __restrict__ F2,
    const float* __restrict__ A1,
    const int* __restrict__ maskI,
    float* __restrict__ M4_t, float* __restrict__ bias_t,
    float* __restrict__ M4_s, float* __restrict__ bias_s,
    _Float16* __restrict__ Wfrag,
    float* __restrict__ F1T, float* __restrict__ F2T,
    float* __restrict__ A1T,
    float* __restrict__ okb)
{
  const int tid = threadIdx.x;
  const int blk = blockIdx.x;
  if (blk == 0) {
    for (int g = tid; g < G_; g += 256) {
      float m0=0.f,m1=0.f,bt=0.f;
      for (int e=0;e<H_;e++){ float w=Wih_t[g*H_+e]; m0+=w*W_sp[e*2]; m1+=w*W_sp[e*2+1]; bt+=w*b_sp[e]; }
      M4_t[g*4+0]=m0; M4_t[g*4+1]=m1; M4_t[g*4+2]=0.f; M4_t[g*4+3]=0.f;
      bias_t[g]=bt+bih_t[g]+bhh_t[g];
      float s0=0.f,s1=0.f,s2=0.f,s3=0.f,bs=0.f;
      for (int e=0;e<H_;e++){ float w=Wih_s[g*H_+e]; s0+=w*W_st[e*4]; s1+=w*W_st[e*4+1]; s2+=w*W_st[e*4+2]; s3+=w*W_st[e*4+3]; bs+=w*b_st[e]; }
      M4_s[g*4+0]=s0; M4_s[g*4+1]=s1; M4_s[g*4+2]=s2; M4_s[g*4+3]=s3;
      bias_s[g]=bs+bih_s[g]+bhh_s[g];
    }
  } else if (blk <= 8) {
    const int L = (blk-1) >> 2;           // lstm
    const int q = (blk-1) & 3;            // quarter
    const float* Whh = L ? Whh_s : Whh_t;
    for (int e = q*16384 + tid; e < (q+1)*16384; e += 256) {
      const int j  = e & 7;
      const int l  = (e >> 3) & 63;
      const int t  = (e >> 9) & 3;
      const int n  = (e >> 11) & 3;
      const int w  = (e >> 13) & 7;
      const int g  = n*128 + w*16 + (l & 15);
      const int k  = t*32 + 8*(l >> 4) + j;
      Wfrag[L*65536 + e] = (_Float16)Whh[g*H_ + k];
    }
  } else if (blk == 9) {
    for (int idx = tid; idx < H_*2*H_; idx += 256) { // F1 (128,256)
      int j = idx >> 8, k = idx & 255;
      F1T[k*H_+j] = F1[idx];
    }
  } else if (blk == 10) {
    for (int idx = tid; idx < H_*H_; idx += 256) {  // F2 (128,128)
      int j = idx >> 7, k = idx & 127;
      F2T[k*H_+j] = F2[idx];
    }
  } else if (blk == 15) {
    for (int idx = tid; idx < H_*2*H_; idx += 256) { // A1 (128,256)
      int j = idx >> 8, k = idx & 255;
      A1T[k*H_+j] = A1[idx];
    }
  } else {
    const int n = (blk-11)*256 + tid;
    int cnt = 0;
    for (int t=0;t<T_;t++) cnt += (maskI[t*N_ + n] > 0);
    okb[n] = (cnt >= 2) ? 1.f : 0.f;
  }
}

// ---------------- Kernel 1: both masked LSTMs, MFMA, weights in VGPRs ----------------
__global__ __launch_bounds__(512, 2) void lstm_kernel(
    const float* __restrict__ rel, const float* __restrict__ pvx,
    const float* __restrict__ pvy, const float* __restrict__ pax,
    const float* __restrict__ pay, const int* __restrict__ maskI,
    const float* __restrict__ M4_t, const float* __restrict__ bias_t,
    const float* __restrict__ M4_s, const float* __restrict__ bias_s,
    const _Float16* __restrict__ Wfrag,
    float* __restrict__ h_t_out, float* __restrict__ h_s_out)
{
  __shared__ _Float16 hA[2][2][4][64][8] __align__(16);  // [buf][hi/lo][ktile][lane][j] 16KB
  __shared__ float4 xsh[T_][8];                          // x per (t, row) 8KB
  __shared__ unsigned int ml[T_];                        // mask bits per t

  const int lstm = blockIdx.y;
  const int tid  = threadIdx.x;
  const int w    = tid >> 6;
  const int l    = tid & 63;
  const int n0   = blockIdx.x * 8;
  const int u    = w*16 + (l & 15);      // unit this lane owns for activation
  const int kt_u = u >> 5;
  const int r0   = (l >> 4) * 4;

  const float* M4   = lstm ? M4_s   : M4_t;
  const float* bias = lstm ? bias_s : bias_t;

  // ---- load B fragments (weights) into VGPRs: 4 ntile x 4 ktile x half8 ----
  half8 bw[4][4];
  #pragma unroll
  for (int n=0;n<4;n++)
    #pragma unroll
    for (int t=0;t<4;t++){
      const int base = ((((lstm*8 + w)*4 + n)*4 + t)*64 + l)*8;
      bw[n][t] = *(const half8*)(Wfrag + base);
    }

  // per-gate bias and input-projection rows for this lane's 4 gate-types
  float bb[4]; float4 mvn[4];
  #pragma unroll
  for (int n=0;n<4;n++){
    const int g = n*128 + u;
    bb[n]  = bias[g];
    mvn[n] = *(const float4*)(M4 + g*4);
  }

  // ---- stage x and mask into LDS ----
  {
    const int t = tid >> 3, r = tid & 7;
    const int n = n0 + r, b = n >> 5, p = n & 31;
    float4 xv;
    if (lstm == 0){
      xv.x = rel[(t*B_+b)*64 + p];
      xv.y = rel[(t*B_+b)*64 + 32 + p];
      xv.z = 0.f; xv.w = 0.f;
    } else {
      const int i0 = t*N_ + n;
      xv.x = pvx[i0]; xv.y = pvy[i0]; xv.z = pax[i0]; xv.w = pay[i0];
    }
    xsh[t][r] = xv;
    if (tid < T_){
      unsigned int mw = 0;
      for (int rr=0; rr<8; rr++) mw |= (maskI[tid*N_ + n0 + rr] > 0) ? (1u<<rr) : 0u;
      ml[tid] = mw;
    }
  }
  // zero both h buffers (8192 halves = 4096 u32)
  {
    unsigned int* hz = (unsigned int*)&hA[0][0][0][0][0];
    #pragma unroll
    for (int i=0;i<8;i++) hz[tid + i*512] = 0u;
  }
  float c0=0.f,c1=0.f,c2=0.f,c3=0.f;
  __syncthreads();

  for (int t=0; t<T_; ++t){
    const int cur = t & 1, nxt = cur ^ 1;
    const unsigned int mw = ml[t];

    // x for this lane's 4 rows (rows>=8 read clamped; results unused)
    float4 xv0 = xsh[t][(r0+0)&7];
    float4 xv1 = xsh[t][(r0+1)&7];
    float4 xv2 = xsh[t][(r0+2)&7];
    float4 xv3 = xsh[t][(r0+3)&7];

    f32x4 acc[4];
    #pragma unroll
    for (int n=0;n<4;n++){
      acc[n][0] = bb[n] + mvn[n].x*xv0.x + mvn[n].y*xv0.y + mvn[n].z*xv0.z + mvn[n].w*xv0.w;
      acc[n][1] = bb[n] + mvn[n].x*xv1.x + mvn[n].y*xv1.y + mvn[n].z*xv1.z + mvn[n].w*xv1.w;
      acc[n][2] = bb[n] + mvn[n].x*xv2.x + mvn[n].y*xv2.y + mvn[n].z*xv2.z + mvn[n].w*xv2.w;
      acc[n][3] = bb[n] + mvn[n].x*xv3.x + mvn[n].y*xv3.y + mvn[n].z*xv3.z + mvn[n].w*xv3.w;
    }

    // A fragments: h hi/lo
    half8 ah[4], al[4];
    #pragma unroll
    for (int kt=0;kt<4;kt++){
      ah[kt] = *(const half8*)&hA[cur][0][kt][l][0];
      al[kt] = *(const half8*)&hA[cur][1][kt][l][0];
    }

    #pragma unroll
    for (int n=0;n<4;n++)
      #pragma unroll
      for (int kt=0;kt<4;kt++){
        acc[n] = __builtin_amdgcn_mfma_f32_16x16x32_f16(ah[kt], bw[n][kt], acc[n], 0, 0, 0);
        acc[n] = __builtin_amdgcn_mfma_f32_16x16x32_f16(al[kt], bw[n][kt], acc[n], 0, 0, 0);
      }

    // in-register activation; lane owns (rows r0..r0+3, unit u)
    float cc[4] = {c0,c1,c2,c3};
    #pragma unroll
    for (int i=0;i<4;i++){
      const int row = r0 + i;
      const float ig = acc[0][i], fg = acc[1][i], gv = acc[2][i], og = acc[3][i];
      const float cn = sigm(fg)*cc[i] + sigm(ig)*tanh_fast(gv);
      const float hn = sigm(og)*tanh_fast(cn);
      const int mb = (mw >> (row & 7)) & 1;
      if (mb) cc[i] = cn;
      const _Float16 nh = (_Float16)hn;
      const _Float16 nl = (_Float16)(hn - (float)nh);
      const int lpp = (row & 15) + 16*((u >> 3) & 3);
      const int jj = u & 7;
      const _Float16 oh = hA[cur][0][kt_u][lpp][jj];
      const _Float16 ol = hA[cur][1][kt_u][lpp][jj];
      hA[nxt][0][kt_u][lpp][jj] = mb ? nh : oh;
      hA[nxt][1][kt_u][lpp][jj] = mb ? nl : ol;
    }
    c0=cc[0]; c1=cc[1]; c2=cc[2]; c3=cc[3];
    __syncthreads();
  }

  // final h lives in buffer 0 (t=63 wrote nxt=0)
  float* hout = lstm ? h_s_out : h_t_out;
  if (l < 32){
    #pragma unroll
    for (int i=0;i<4;i++){
      const int row = r0 + i;                // 0..7
      const int lpp = row + 16*((u >> 3) & 3);
      const int jj = u & 7;
      const float hv = (float)hA[0][0][kt_u][lpp][jj] + (float)hA[0][1][kt_u][lpp][jj];
      hout[(n0+row)*H_ + u] = hv;
    }
  }
}

// ---------------- Kernel 2: fused = relu(relu([h_t,h_s]@F1T+f1)@F2T+f2) * ok ----------------
__global__ __launch_bounds__(128) void fuse_kernel(
    const float* __restrict__ h_t, const float* __restrict__ h_s,
    const float* __restrict__ F1T, const float* __restrict__ f1,
    const float* __restrict__ F2T, const float* __restrict__ f2,
    const float* __restrict__ okb, float* __restrict__ fused)
{
  const int n = blockIdx.x, j = threadIdx.x;
  __shared__ float comb[2*H_];
  __shared__ float hid[H_];
  comb[j]      = h_t[n*H_+j];
  comb[H_+j]   = h_s[n*H_+j];
  __syncthreads();
  float acc = f1[j];
  #pragma unroll 8
  for (int k=0;k<2*H_;k++) acc += comb[k]*F1T[k*H_+j];
  hid[j] = fmaxf(acc, 0.f);
  __syncthreads();
  float acc2 = f2[j];
  #pragma unroll 8
  for (int k=0;k<H_;k++) acc2 += hid[k]*F2T[k*H_+j];
  fused[n*H_+j] = fmaxf(acc2, 0.f) * okb[n];
}

// ---------------- Kernel 3a: per-batch mean of fused over valid rows ----------------
__global__ __launch_bounds__(128) void mean_kernel(
    const float* __restrict__ fused, const float* __restrict__ okb,
    float* __restrict__ mean)
{
  const int b = blockIdx.x, j = threadIdx.x;
  float s = 0.f;
  #pragma unroll 8
  for (int p=0;p<P_;p++) s += fused[(b*P_+p)*H_ + j];   // invalid rows already 0
  float nv = 0.f;
  #pragma unroll
  for (int p=0;p<P_;p++) nv += okb[b*P_+p];
  mean[b*H_+j] = s / fmaxf(nv, 1.f);
}

// ---------------- Kernel 3b: score per row (one block per (b,p)) ----------------
__global__ __launch_bounds__(128) void score_kernel(
    const float* __restrict__ fused, const float* __restrict__ mean,
    const float* __restrict__ okb,
    const float* __restrict__ A1T, const float* __restrict__ a1,
    const float* __restrict__ A2, const float* __restrict__ a2v,
    float* __restrict__ score)
{
  const int n = blockIdx.x, b = n >> 5, j = threadIdx.x;
  __shared__ float comb[2*H_];
  __shared__ float red[2];
  comb[j]      = fused[n*H_ + j];
  comb[H_+j]   = mean[b*H_ + j];
  __syncthreads();
  float acc = a1[j];
  #pragma unroll 8
  for (int k=0;k<2*H_;k++) acc += comb[k]*A1T[k*H_+j];
  float v = fmaxf(acc, 0.f) * A2[j];
  // reduce within each 64-lane wave, then across the 2 waves via LDS
  #pragma unroll
  for (int off=32; off>=1; off>>=1) v += __shfl_down(v, off, 64);
  if ((j & 63) == 0) red[j >> 6] = v;
  __syncthreads();
  if (j == 0){
    const float s = fmaxf(red[0] + red[1] + a2v[0], 0.f);
    score[n] = (okb[n] > 0.f) ? s : -1e9f;
  }
}

// ---------------- Kernel 3c: softmax over rows + weighted sum ----------------
__global__ __launch_bounds__(128) void final_kernel(
    const float* __restrict__ fused, const float* __restrict__ score,
    const float* __restrict__ okb, float* __restrict__ out)
{
  const int b = blockIdx.x, j = threadIdx.x;
  __shared__ float wgt[P_];
  if (j < P_){
    const float s = score[b*P_+j];
    const float ok = okb[b*P_+j];
    float mx = s;
    #pragma unroll
    for (int off=16; off>=1; off>>=1) mx = fmaxf(mx, __shfl_xor(mx, off, 32));
    float e = (ok > 0.f) ? __expf(s - mx) : 0.f;
    float se = e;
    #pragma unroll
    for (int off=16; off>=1; off>>=1) se += __shfl_xor(se, off, 32);
    wgt[j] = e / fmaxf(se, 1e-9f);
  }
  __syncthreads();
  float acc = 0.f;
  #pragma unroll 8
  for (int p=0;p<P_;p++) acc += wgt[p]*fused[(b*P_+p)*H_ + j];
  out[b*H_+j] = acc;
}

extern "C" void kernel_launch(void* const* d_in, const int* in_sizes, int n_in,
                              void* d_out, int out_size, void* d_ws, size_t ws_size,
                              hipStream_t stream) {
  const float* rel   = (const float*)d_in[1];
  const float* pvx   = (const float*)d_in[2];
  const float* pvy   = (const float*)d_in[3];
  const float* pax   = (const float*)d_in[4];
  const float* pay   = (const float*)d_in[5];
  const int*   pmask = (const int*)  d_in[6];
  const float* W_sp  = (const float*)d_in[7];
  const float* b_sp  = (const float*)d_in[8];
  const float* W_st  = (const float*)d_in[9];
  const float* b_st  = (const float*)d_in[10];
  const float* Wih_t = (const float*)d_in[11];
  const float* Whh_t = (const float*)d_in[12];
  const float* bih_t = (const float*)d_in[13];
  const float* bhh_t = (const float*)d_in[14];
  const float* Wih_s = (const float*)d_in[15];
  const float* Whh_s = (const float*)d_in[16];
  const float* bih_s = (const float*)d_in[17];
  const float* bhh_s = (const float*)d_in[18];
  const float* A1    = (const float*)d_in[19];
  const float* a1    = (const float*)d_in[20];
  const float* A2    = (const float*)d_in[21];
  const float* a2v   = (const float*)d_in[22];
  const float* F1    = (const float*)d_in[23];
  const float* f1    = (const float*)d_in[24];
  const float* F2    = (const float*)d_in[25];
  const float* f2    = (const float*)d_in[26];

  float* ws = (float*)d_ws;
  size_t off = 0;
  _Float16* Wfrag = (_Float16*)(ws + off); off += 65536;   // 131072 f16
  float* M4_t   = ws + off; off += (size_t)G_*4;
  float* M4_s   = ws + off; off += (size_t)G_*4;
  float* bias_t = ws + off; off += G_;
  float* bias_s = ws + off; off += G_;
  float* F1T    = ws + off; off += (size_t)2*H_*H_;
  float* F2T    = ws + off; off += (size_t)H_*H_;
  float* A1T    = ws + off; off += (size_t)2*H_*H_;
  float* h_t    = ws + off; off += (size_t)N_*H_;
  float* h_s    = ws + off; off += (size_t)N_*H_;
  float* fusedb = ws + off; off += (size_t)N_*H_;
  float* meanb  = ws + off; off += (size_t)B_*H_;
  float* scoreb = ws + off; off += N_;
  float* okb    = ws + off; off += N_;

  hipLaunchKernelGGL(prep_kernel, dim3(16), dim3(256), 0, stream,
      W_sp, b_sp, W_st, b_st, Wih_t, Whh_t, bih_t, bhh_t,
      Wih_s, Whh_s, bih_s, bhh_s, F1, F2, A1, pmask,
      M4_t, bias_t, M4_s, bias_s, Wfrag, F1T, F2T, A1T, okb);

  hipLaunchKernelGGL(lstm_kernel, dim3(N_/8, 2), dim3(512), 0, stream,
      rel, pvx, pvy, pax, pay, pmask,
      M4_t, bias_t, M4_s, bias_s, Wfrag,
      h_t, h_s);

  hipLaunchKernelGGL(fuse_kernel, dim3(N_), dim3(128), 0, stream,
      h_t, h_s, F1T, f1, F2T, f2, okb, fusedb);

  hipLaunchKernelGGL(mean_kernel, dim3(B_), dim3(128), 0, stream,
      fusedb, okb, meanb);

  hipLaunchKernelGGL(score_kernel, dim3(N_), dim3(128), 0, stream,
      fusedb, meanb, okb, A1T, a1, A2, a2v, scoreb);

  hipLaunchKernelGGL(final_kernel, dim3(B_), dim3(128), 0, stream,
      fusedb, scoreb, okb, (float*)d_out);
}

// Round 5
// 150.842 us; speedup vs baseline: 23.0900x; 1.3125x over previous
//
#include <hip/hip_runtime.h>

#define T_ 64
#define B_ 32
#define P_ 32
#define N_ 1024
#define H_ 128
#define G_ 512   // 4*H

typedef __attribute__((ext_vector_type(8))) _Float16 half8;
typedef __attribute__((ext_vector_type(4))) float f32x4;

__device__ __forceinline__ float rcpf(float x){ return __builtin_amdgcn_rcpf(x); }
__device__ __forceinline__ float sigm(float x){ return rcpf(1.f+__expf(-x)); }
__device__ __forceinline__ float tanh_fast(float x){ return 1.f - 2.f*rcpf(__expf(2.f*x)+1.f); }

// ---------------- Kernel 0: prep ----------------
// blk 0: fold input projections -> M4 (G,4) + bias (G)
// blk 1-8: W fragments, f16, MFMA B-layout: [L][w][n][t][lane][j]
//          g = n*128 + w*16 + (lane&15), k = t*32 + 8*(lane>>4) + j
// blk 9: F1T, blk 10: F2T, blk 11-14: okb, blk 15: A1T
__global__ __launch_bounds__(256) void prep_kernel(
    const float* __restrict__ W_sp, const float* __restrict__ b_sp,
    const float* __restrict__ W_st, const float* __restrict__ b_st,
    const float* __restrict__ Wih_t, const float* __restrict__ Whh_t,
    const float* __restrict__ bih_t, const float* __restrict__ bhh_t,
    const float* __restrict__ Wih_s, const float* __restrict__ Whh_s,
    const float* __restrict__ bih_s, const float* __restrict__ bhh_s,
    const float* __restrict__ F1, const float* __restrict__ F2,
    const float* __restrict__ A1,
    const int* __restrict__ maskI,
    float* __restrict__ M4_t, float* __restrict__ bias_t,
    float* __restrict__ M4_s, float* __restrict__ bias_s,
    _Float16* __restrict__ Wfrag,
    float* __restrict__ F1T, float* __restrict__ F2T,
    float* __restrict__ A1T,
    float* __restrict__ okb)
{
  const int tid = threadIdx.x;
  const int blk = blockIdx.x;
  if (blk == 0) {
    for (int g = tid; g < G_; g += 256) {
      float m0=0.f,m1=0.f,bt=0.f;
      for (int e=0;e<H_;e++){ float w=Wih_t[g*H_+e]; m0+=w*W_sp[e*2]; m1+=w*W_sp[e*2+1]; bt+=w*b_sp[e]; }
      M4_t[g*4+0]=m0; M4_t[g*4+1]=m1; M4_t[g*4+2]=0.f; M4_t[g*4+3]=0.f;
      bias_t[g]=bt+bih_t[g]+bhh_t[g];
      float s0=0.f,s1=0.f,s2=0.f,s3=0.f,bs=0.f;
      for (int e=0;e<H_;e++){ float w=Wih_s[g*H_+e]; s0+=w*W_st[e*4]; s1+=w*W_st[e*4+1]; s2+=w*W_st[e*4+2]; s3+=w*W_st[e*4+3]; bs+=w*b_st[e]; }
      M4_s[g*4+0]=s0; M4_s[g*4+1]=s1; M4_s[g*4+2]=s2; M4_s[g*4+3]=s3;
      bias_s[g]=bs+bih_s[g]+bhh_s[g];
    }
  } else if (blk <= 8) {
    const int L = (blk-1) >> 2;           // lstm
    const int q = (blk-1) & 3;            // quarter
    const float* Whh = L ? Whh_s : Whh_t;
    for (int e = q*16384 + tid; e < (q+1)*16384; e += 256) {
      const int j  = e & 7;
      const int l  = (e >> 3) & 63;
      const int t  = (e >> 9) & 3;
      const int n  = (e >> 11) & 3;
      const int w  = (e >> 13) & 7;
      const int g  = n*128 + w*16 + (l & 15);
      const int k  = t*32 + 8*(l >> 4) + j;
      Wfrag[L*65536 + e] = (_Float16)Whh[g*H_ + k];
    }
  } else if (blk == 9) {
    for (int idx = tid; idx < H_*2*H_; idx += 256) { // F1 (128,256)
      int j = idx >> 8, k = idx & 255;
      F1T[k*H_+j] = F1[idx];
    }
  } else if (blk == 10) {
    for (int idx = tid; idx < H_*H_; idx += 256) {  // F2 (128,128)
      int j = idx >> 7, k = idx & 127;
      F2T[k*H_+j] = F2[idx];
    }
  } else if (blk == 15) {
    for (int idx = tid; idx < H_*2*H_; idx += 256) { // A1 (128,256)
      int j = idx >> 8, k = idx & 255;
      A1T[k*H_+j] = A1[idx];
    }
  } else {
    const int n = (blk-11)*256 + tid;
    int cnt = 0;
    for (int t=0;t<T_;t++) cnt += (maskI[t*N_ + n] > 0);
    okb[n] = (cnt >= 2) ? 1.f : 0.f;
  }
}

// ---------------- Kernel 1: both masked LSTMs, MFMA, weights in VGPRs ----------------
// grid (128, 2): x = 8-row chunk, y = lstm. 512 threads = 8 waves.
// wave w owns units u = w*16 + (lane&15); ntile n = gate type n (i,f,g,o).
// Lane holds C rows r0..r0+3 (r0=(lane>>4)*4; rows 8-15 pad).
// h kept as f16 hi+lo: in LDS (A-frag layout, double-buffered) for MFMA,
// and in registers (rh/rl) for this lane's own cells (no old-value LDS reads).
__global__ __launch_bounds__(512, 2) void lstm_kernel(
    const float* __restrict__ rel, const float* __restrict__ pvx,
    const float* __restrict__ pvy, const float* __restrict__ pax,
    const float* __restrict__ pay, const int* __restrict__ maskI,
    const float* __restrict__ M4_t, const float* __restrict__ bias_t,
    const float* __restrict__ M4_s, const float* __restrict__ bias_s,
    const _Float16* __restrict__ Wfrag,
    float* __restrict__ h_t_out, float* __restrict__ h_s_out)
{
  __shared__ _Float16 hA[2][2][4][64][8] __align__(16);  // [buf][hi/lo][ktile][lane][j] 16KB
  __shared__ float4 xsh[T_][8];                          // x per (t, row) 8KB
  __shared__ unsigned int ml[T_];                        // mask bits per t

  const int lstm = blockIdx.y;
  const int tid  = threadIdx.x;
  const int w    = tid >> 6;
  const int l    = tid & 63;
  const int n0   = blockIdx.x * 8;
  const int u    = w*16 + (l & 15);      // unit this lane owns for activation
  const int kt_u = u >> 5;
  const int r0   = (l >> 4) * 4;

  const float* M4   = lstm ? M4_s   : M4_t;
  const float* bias = lstm ? bias_s : bias_t;

  // ---- load B fragments (weights) into VGPRs: 4 ntile x 4 ktile x half8 ----
  half8 bw[4][4];
  #pragma unroll
  for (int n=0;n<4;n++)
    #pragma unroll
    for (int t=0;t<4;t++){
      const int base = ((((lstm*8 + w)*4 + n)*4 + t)*64 + l)*8;
      bw[n][t] = *(const half8*)(Wfrag + base);
    }

  // per-gate bias and input-projection rows for this lane's 4 gate-types
  float bb[4]; float4 mvn[4];
  #pragma unroll
  for (int n=0;n<4;n++){
    const int g = n*128 + u;
    bb[n]  = bias[g];
    mvn[n] = *(const float4*)(M4 + g*4);
  }

  // per-i LDS half-offsets for this lane's cells (loop-invariant)
  // offset(buf,hl,kt,lane,j) = ((buf*2+hl)*4+kt)*512/ ... in halves:
  // buf stride 4096, hl stride 2048, then kt*512 + lane*8 + j
  int hoff[4];
  #pragma unroll
  for (int i=0;i<4;i++){
    const int lpp = ((r0+i) & 15) + 16*((u >> 3) & 3);
    hoff[i] = kt_u*512 + lpp*8 + (u & 7);
  }
  _Float16* hbase = &hA[0][0][0][0][0];

  // ---- stage x and mask into LDS ----
  {
    const int t = tid >> 3, r = tid & 7;
    const int n = n0 + r, b = n >> 5, p = n & 31;
    float4 xv;
    if (lstm == 0){
      xv.x = rel[(t*B_+b)*64 + p];
      xv.y = rel[(t*B_+b)*64 + 32 + p];
      xv.z = 0.f; xv.w = 0.f;
    } else {
      const int i0 = t*N_ + n;
      xv.x = pvx[i0]; xv.y = pvy[i0]; xv.z = pax[i0]; xv.w = pay[i0];
    }
    xsh[t][r] = xv;
    if (tid < T_){
      unsigned int mw = 0;
      for (int rr=0; rr<8; rr++) mw |= (maskI[tid*N_ + n0 + rr] > 0) ? (1u<<rr) : 0u;
      ml[tid] = mw;
    }
  }
  // zero both h buffers (8192 halves = 4096 u32)
  {
    unsigned int* hz = (unsigned int*)hbase;
    #pragma unroll
    for (int i=0;i<8;i++) hz[tid + i*512] = 0u;
  }
  float cc[4] = {0.f,0.f,0.f,0.f};
  _Float16 rh[4] = {(_Float16)0.f,(_Float16)0.f,(_Float16)0.f,(_Float16)0.f};
  _Float16 rl[4] = {(_Float16)0.f,(_Float16)0.f,(_Float16)0.f,(_Float16)0.f};
  __syncthreads();

  #pragma unroll 2
  for (int t=0; t<T_; ++t){
    const int cur = t & 1, nxt = cur ^ 1;
    const unsigned int mw = ml[t];

    // x for this lane's 4 rows (rows>=8 read wrapped; results unused)
    float4 xv0 = xsh[t][(r0+0)&7];
    float4 xv1 = xsh[t][(r0+1)&7];
    float4 xv2 = xsh[t][(r0+2)&7];
    float4 xv3 = xsh[t][(r0+3)&7];

    f32x4 acc[4];
    #pragma unroll
    for (int n=0;n<4;n++){
      acc[n][0] = bb[n] + mvn[n].x*xv0.x + mvn[n].y*xv0.y + mvn[n].z*xv0.z + mvn[n].w*xv0.w;
      acc[n][1] = bb[n] + mvn[n].x*xv1.x + mvn[n].y*xv1.y + mvn[n].z*xv1.z + mvn[n].w*xv1.w;
      acc[n][2] = bb[n] + mvn[n].x*xv2.x + mvn[n].y*xv2.y + mvn[n].z*xv2.z + mvn[n].w*xv2.w;
      acc[n][3] = bb[n] + mvn[n].x*xv3.x + mvn[n].y*xv3.y + mvn[n].z*xv3.z + mvn[n].w*xv3.w;
    }

    // A fragments: h hi/lo
    half8 ah[4], al[4];
    #pragma unroll
    for (int kt=0;kt<4;kt++){
      ah[kt] = *(const half8*)&hA[cur][0][kt][l][0];
      al[kt] = *(const half8*)&hA[cur][1][kt][l][0];
    }

    // 8 virtual k-passes (hi 0..3, lo 0..3), n inner for dep spacing 4
    #pragma unroll
    for (int v=0;v<8;v++){
      const half8 av = (v < 4) ? ah[v] : al[v-4];
      const int kt = v & 3;
      #pragma unroll
      for (int n=0;n<4;n++)
        acc[n] = __builtin_amdgcn_mfma_f32_16x16x32_f16(av, bw[n][kt], acc[n], 0, 0, 0);
    }

    // in-register activation; lane owns (rows r0..r0+3, unit u)
    #pragma unroll
    for (int i=0;i<4;i++){
      const float ig = acc[0][i], fg = acc[1][i], gv = acc[2][i], og = acc[3][i];
      const float cn = sigm(fg)*cc[i] + sigm(ig)*tanh_fast(gv);
      const float hn = sigm(og)*tanh_fast(cn);
      const int mb = (mw >> ((r0+i) & 7)) & 1;
      const _Float16 nh = (_Float16)hn;
      const _Float16 nl = (_Float16)(hn - (float)nh);
      cc[i] = mb ? cn : cc[i];
      rh[i] = mb ? nh : rh[i];
      rl[i] = mb ? nl : rl[i];
      hbase[nxt*4096 +    0 + hoff[i]] = rh[i];
      hbase[nxt*4096 + 2048 + hoff[i]] = rl[i];
    }
    __syncthreads();
  }

  // output this lane's own cells from registers (rows 0..7 real)
  float* hout = lstm ? h_s_out : h_t_out;
  if (l < 32){
    #pragma unroll
    for (int i=0;i<4;i++){
      const int row = r0 + i;                // 0..7
      hout[(n0+row)*H_ + u] = (float)rh[i] + (float)rl[i];
    }
  }
}

// ---------------- Kernel 2: fused = relu(relu([h_t,h_s]@F1T+f1)@F2T+f2) * ok ----------------
__global__ __launch_bounds__(128) void fuse_kernel(
    const float* __restrict__ h_t, const float* __restrict__ h_s,
    const float* __restrict__ F1T, const float* __restrict__ f1,
    const float* __restrict__ F2T, const float* __restrict__ f2,
    const float* __restrict__ okb, float* __restrict__ fused)
{
  const int n = blockIdx.x, j = threadIdx.x;
  __shared__ float comb[2*H_];
  __shared__ float hid[H_];
  comb[j]      = h_t[n*H_+j];
  comb[H_+j]   = h_s[n*H_+j];
  __syncthreads();
  float acc = f1[j];
  #pragma unroll 8
  for (int k=0;k<2*H_;k++) acc += comb[k]*F1T[k*H_+j];
  hid[j] = fmaxf(acc, 0.f);
  __syncthreads();
  float acc2 = f2[j];
  #pragma unroll 8
  for (int k=0;k<H_;k++) acc2 += hid[k]*F2T[k*H_+j];
  fused[n*H_+j] = fmaxf(acc2, 0.f) * okb[n];
}

// ---------------- Kernel 3a: per-batch mean of fused over valid rows ----------------
__global__ __launch_bounds__(128) void mean_kernel(
    const float* __restrict__ fused, const float* __restrict__ okb,
    float* __restrict__ mean)
{
  const int b = blockIdx.x, j = threadIdx.x;
  float s = 0.f;
  #pragma unroll 8
  for (int p=0;p<P_;p++) s += fused[(b*P_+p)*H_ + j];   // invalid rows already 0
  float nv = 0.f;
  #pragma unroll
  for (int p=0;p<P_;p++) nv += okb[b*P_+p];
  mean[b*H_+j] = s / fmaxf(nv, 1.f);
}

// ---------------- Kernel 3b: score per row (one block per (b,p)) ----------------
__global__ __launch_bounds__(128) void score_kernel(
    const float* __restrict__ fused, const float* __restrict__ mean,
    const float* __restrict__ okb,
    const float* __restrict__ A1T, const float* __restrict__ a1,
    const float* __restrict__ A2, const float* __restrict__ a2v,
    float* __restrict__ score)
{
  const int n = blockIdx.x, b = n >> 5, j = threadIdx.x;
  __shared__ float comb[2*H_];
  __shared__ float red[2];
  comb[j]      = fused[n*H_ + j];
  comb[H_+j]   = mean[b*H_ + j];
  __syncthreads();
  float acc = a1[j];
  #pragma unroll 8
  for (int k=0;k<2*H_;k++) acc += comb[k]*A1T[k*H_+j];
  float v = fmaxf(acc, 0.f) * A2[j];
  // reduce within each 64-lane wave, then across the 2 waves via LDS
  #pragma unroll
  for (int off=32; off>=1; off>>=1) v += __shfl_down(v, off, 64);
  if ((j & 63) == 0) red[j >> 6] = v;
  __syncthreads();
  if (j == 0){
    const float s = fmaxf(red[0] + red[1] + a2v[0], 0.f);
    score[n] = (okb[n] > 0.f) ? s : -1e9f;
  }
}

// ---------------- Kernel 3c: softmax over rows + weighted sum ----------------
__global__ __launch_bounds__(128) void final_kernel(
    const float* __restrict__ fused, const float* __restrict__ score,
    const float* __restrict__ okb, float* __restrict__ out)
{
  const int b = blockIdx.x, j = threadIdx.x;
  __shared__ float wgt[P_];
  if (j < P_){
    const float s = score[b*P_+j];
    const float ok = okb[b*P_+j];
    float mx = s;
    #pragma unroll
    for (int off=16; off>=1; off>>=1) mx = fmaxf(mx, __shfl_xor(mx, off, 32));
    float e = (ok > 0.f) ? __expf(s - mx) : 0.f;
    float se = e;
    #pragma unroll
    for (int off=16; off>=1; off>>=1) se += __shfl_xor(se, off, 32);
    wgt[j] = e / fmaxf(se, 1e-9f);
  }
  __syncthreads();
  float acc = 0.f;
  #pragma unroll 8
  for (int p=0;p<P_;p++) acc += wgt[p]*fused[(b*P_+p)*H_ + j];
  out[b*H_+j] = acc;
}

extern "C" void kernel_launch(void* const* d_in, const int* in_sizes, int n_in,
                              void* d_out, int out_size, void* d_ws, size_t ws_size,
                              hipStream_t stream) {
  const float* rel   = (const float*)d_in[1];
  const float* pvx   = (const float*)d_in[2];
  const float* pvy   = (const float*)d_in[3];
  const float* pax   = (const float*)d_in[4];
  const float* pay   = (const float*)d_in[5];
  const int*   pmask = (const int*)  d_in[6];
  const float* W_sp  = (const float*)d_in[7];
  const float* b_sp  = (const float*)d_in[8];
  const float* W_st  = (const float*)d_in[9];
  const float* b_st  = (const float*)d_in[10];
  const float* Wih_t = (const float*)d_in[11];
  const float* Whh_t = (const float*)d_in[12];
  const float* bih_t = (const float*)d_in[13];
  const float* bhh_t = (const float*)d_in[14];
  const float* Wih_s = (const float*)d_in[15];
  const float* Whh_s = (const float*)d_in[16];
  const float* bih_s = (const float*)d_in[17];
  const float* bhh_s = (const float*)d_in[18];
  const float* A1    = (const float*)d_in[19];
  const float* a1    = (const float*)d_in[20];
  const float* A2    = (const float*)d_in[21];
  const float* a2v   = (const float*)d_in[22];
  const float* F1    = (const float*)d_in[23];
  const float* f1    = (const float*)d_in[24];
  const float* F2    = (const float*)d_in[25];
  const float* f2    = (const float*)d_in[26];

  float* ws = (float*)d_ws;
  size_t off = 0;
  _Float16* Wfrag = (_Float16*)(ws + off); off += 65536;   // 131072 f16
  float* M4_t   = ws + off; off += (size_t)G_*4;
  float* M4_s   = ws + off; off += (size_t)G_*4;
  float* bias_t = ws + off; off += G_;
  float* bias_s = ws + off; off += G_;
  float* F1T    = ws + off; off += (size_t)2*H_*H_;
  float* F2T    = ws + off; off += (size_t)H_*H_;
  float* A1T    = ws + off; off += (size_t)2*H_*H_;
  float* h_t    = ws + off; off += (size_t)N_*H_;
  float* h_s    = ws + off; off += (size_t)N_*H_;
  float* fusedb = ws + off; off += (size_t)N_*H_;
  float* meanb  = ws + off; off += (size_t)B_*H_;
  float* scoreb = ws + off; off += N_;
  float* okb    = ws + off; off += N_;

  hipLaunchKernelGGL(prep_kernel, dim3(16), dim3(256), 0, stream,
      W_sp, b_sp, W_st, b_st, Wih_t, Whh_t, bih_t, bhh_t,
      Wih_s, Whh_s, bih_s, bhh_s, F1, F2, A1, pmask,
      M4_t, bias_t, M4_s, bias_s, Wfrag, F1T, F2T, A1T, okb);

  hipLaunchKernelGGL(lstm_kernel, dim3(N_/8, 2), dim3(512), 0, stream,
      rel, pvx, pvy, pax, pay, pmask,
      M4_t, bias_t, M4_s, bias_s, Wfrag,
      h_t, h_s);

  hipLaunchKernelGGL(fuse_kernel, dim3(N_), dim3(128), 0, stream,
      h_t, h_s, F1T, f1, F2T, f2, okb, fusedb);

  hipLaunchKernelGGL(mean_kernel, dim3(B_), dim3(128), 0, stream,
      fusedb, okb, meanb);

  hipLaunchKernelGGL(score_kernel, dim3(N_), dim3(128), 0, stream,
      fusedb, meanb, okb, A1T, a1, A2, a2v, scoreb);

  hipLaunchKernelGGL(final_kernel, dim3(B_), dim3(128), 0, stream,
      fusedb, scoreb, okb, (float*)d_out);
}

// Round 6
// 150.249 us; speedup vs baseline: 23.1811x; 1.0039x over previous
//
#include <hip/hip_runtime.h>

#define T_ 64
#define B_ 32
#define P_ 32
#define N_ 1024
#define H_ 128
#define G_ 512   // 4*H

typedef __attribute__((ext_vector_type(8))) _Float16 half8;
typedef __attribute__((ext_vector_type(4))) float f32x4;

__device__ __forceinline__ float rcpf(float x){ return __builtin_amdgcn_rcpf(x); }
__device__ __forceinline__ float sigm(float x){ return rcpf(1.f+__expf(-x)); }
__device__ __forceinline__ float tanh_fast(float x){ return 1.f - 2.f*rcpf(__expf(2.f*x)+1.f); }

// ---------------- Kernel 0: prep ----------------
// blk 0: fold input projections -> M4 (G,4) + bias (G)
// blk 1-8: W fragments, f16, MFMA B-layout: [L][w][n][t][lane][j]
//          g = n*128 + w*16 + (lane&15), k = t*32 + 8*(lane>>4) + j
// blk 9: F1T, blk 10: F2T, blk 11-14: okb, blk 15: A1T
__global__ __launch_bounds__(256) void prep_kernel(
    const float* __restrict__ W_sp, const float* __restrict__ b_sp,
    const float* __restrict__ W_st, const float* __restrict__ b_st,
    const float* __restrict__ Wih_t, const float* __restrict__ Whh_t,
    const float* __restrict__ bih_t, const float* __restrict__ bhh_t,
    const float* __restrict__ Wih_s, const float* __restrict__ Whh_s,
    const float* __restrict__ bih_s, const float* __restrict__ bhh_s,
    const float* __restrict__ F1, const float* __restrict__ F2,
    const float* __restrict__ A1,
    const int* __restrict__ maskI,
    float* __restrict__ M4_t, float* __restrict__ bias_t,
    float* __restrict__ M4_s, float* __restrict__ bias_s,
    _Float16* __restrict__ Wfrag,
    float* __restrict__ F1T, float* __restrict__ F2T,
    float* __restrict__ A1T,
    float* __restrict__ okb)
{
  const int tid = threadIdx.x;
  const int blk = blockIdx.x;
  if (blk == 0) {
    for (int g = tid; g < G_; g += 256) {
      float m0=0.f,m1=0.f,bt=0.f;
      for (int e=0;e<H_;e++){ float w=Wih_t[g*H_+e]; m0+=w*W_sp[e*2]; m1+=w*W_sp[e*2+1]; bt+=w*b_sp[e]; }
      M4_t[g*4+0]=m0; M4_t[g*4+1]=m1; M4_t[g*4+2]=0.f; M4_t[g*4+3]=0.f;
      bias_t[g]=bt+bih_t[g]+bhh_t[g];
      float s0=0.f,s1=0.f,s2=0.f,s3=0.f,bs=0.f;
      for (int e=0;e<H_;e++){ float w=Wih_s[g*H_+e]; s0+=w*W_st[e*4]; s1+=w*W_st[e*4+1]; s2+=w*W_st[e*4+2]; s3+=w*W_st[e*4+3]; bs+=w*b_st[e]; }
      M4_s[g*4+0]=s0; M4_s[g*4+1]=s1; M4_s[g*4+2]=s2; M4_s[g*4+3]=s3;
      bias_s[g]=bs+bih_s[g]+bhh_s[g];
    }
  } else if (blk <= 8) {
    const int L = (blk-1) >> 2;           // lstm
    const int q = (blk-1) & 3;            // quarter
    const float* Whh = L ? Whh_s : Whh_t;
    for (int e = q*16384 + tid; e < (q+1)*16384; e += 256) {
      const int j  = e & 7;
      const int l  = (e >> 3) & 63;
      const int t  = (e >> 9) & 3;
      const int n  = (e >> 11) & 3;
      const int w  = (e >> 13) & 7;
      const int g  = n*128 + w*16 + (l & 15);
      const int k  = t*32 + 8*(l >> 4) + j;
      Wfrag[L*65536 + e] = (_Float16)Whh[g*H_ + k];
    }
  } else if (blk == 9) {
    for (int idx = tid; idx < H_*2*H_; idx += 256) { // F1 (128,256)
      int j = idx >> 8, k = idx & 255;
      F1T[k*H_+j] = F1[idx];
    }
  } else if (blk == 10) {
    for (int idx = tid; idx < H_*H_; idx += 256) {  // F2 (128,128)
      int j = idx >> 7, k = idx & 127;
      F2T[k*H_+j] = F2[idx];
    }
  } else if (blk == 15) {
    for (int idx = tid; idx < H_*2*H_; idx += 256) { // A1 (128,256)
      int j = idx >> 8, k = idx & 255;
      A1T[k*H_+j] = A1[idx];
    }
  } else {
    const int n = (blk-11)*256 + tid;
    int cnt = 0;
    for (int t=0;t<T_;t++) cnt += (maskI[t*N_ + n] > 0);
    okb[n] = (cnt >= 2) ? 1.f : 0.f;
  }
}

// ---------------- Kernel 1: both masked LSTMs, MFMA, weights in VGPRs ----------------
// grid (128, 2): x = 8-row chunk, y = lstm. 512 threads = 8 waves, 1 block/CU.
// amdgpu_waves_per_eu(2,2): pin occupancy target to exactly what the grid can
// use (2 waves/SIMD) so the allocator gets the full 256-VGPR budget and keeps
// the 64-VGPR weight fragment set resident across the t-loop. At the default
// heuristic it capped at 84 VGPRs and rematerialized the 32 weight loads
// per step, forcing a vmcnt(0) drain at every s_barrier (R5 counters).
__global__ __launch_bounds__(512) __attribute__((amdgpu_waves_per_eu(2,2)))
void lstm_kernel(
    const float* __restrict__ rel, const float* __restrict__ pvx,
    const float* __restrict__ pvy, const float* __restrict__ pax,
    const float* __restrict__ pay, const int* __restrict__ maskI,
    const float* __restrict__ M4_t, const float* __restrict__ bias_t,
    const float* __restrict__ M4_s, const float* __restrict__ bias_s,
    const _Float16* __restrict__ Wfrag,
    float* __restrict__ h_t_out, float* __restrict__ h_s_out)
{
  __shared__ _Float16 hA[2][2][4][64][8] __align__(16);  // [buf][hi/lo][ktile][lane][j] 16KB
  __shared__ float4 xsh[T_][8];                          // x per (t, row) 8KB
  __shared__ unsigned int ml[T_];                        // mask bits per t

  const int lstm = blockIdx.y;
  const int tid  = threadIdx.x;
  const int w    = tid >> 6;
  const int l    = tid & 63;
  const int n0   = blockIdx.x * 8;
  const int u    = w*16 + (l & 15);      // unit this lane owns for activation
  const int kt_u = u >> 5;
  const int r0   = (l >> 4) * 4;

  const float* M4   = lstm ? M4_s   : M4_t;
  const float* bias = lstm ? bias_s : bias_t;

  // ---- load B fragments (weights) into VGPRs: 4 ntile x 4 ktile x half8 ----
  half8 bw[4][4];
  #pragma unroll
  for (int n=0;n<4;n++)
    #pragma unroll
    for (int t=0;t<4;t++){
      const int base = ((((lstm*8 + w)*4 + n)*4 + t)*64 + l)*8;
      bw[n][t] = *(const half8*)(Wfrag + base);
    }

  // per-gate bias and input-projection rows for this lane's 4 gate-types
  float bb[4]; float4 mvn[4];
  #pragma unroll
  for (int n=0;n<4;n++){
    const int g = n*128 + u;
    bb[n]  = bias[g];
    mvn[n] = *(const float4*)(M4 + g*4);
  }

  // per-i LDS half-offsets for this lane's cells (loop-invariant)
  int hoff[4];
  #pragma unroll
  for (int i=0;i<4;i++){
    const int lpp = ((r0+i) & 15) + 16*((u >> 3) & 3);
    hoff[i] = kt_u*512 + lpp*8 + (u & 7);
  }
  _Float16* hbase = &hA[0][0][0][0][0];

  // ---- stage x and mask into LDS ----
  {
    const int t = tid >> 3, r = tid & 7;
    const int n = n0 + r, b = n >> 5, p = n & 31;
    float4 xv;
    if (lstm == 0){
      xv.x = rel[(t*B_+b)*64 + p];
      xv.y = rel[(t*B_+b)*64 + 32 + p];
      xv.z = 0.f; xv.w = 0.f;
    } else {
      const int i0 = t*N_ + n;
      xv.x = pvx[i0]; xv.y = pvy[i0]; xv.z = pax[i0]; xv.w = pay[i0];
    }
    xsh[t][r] = xv;
    if (tid < T_){
      unsigned int mw = 0;
      for (int rr=0; rr<8; rr++) mw |= (maskI[tid*N_ + n0 + rr] > 0) ? (1u<<rr) : 0u;
      ml[tid] = mw;
    }
  }
  // zero both h buffers (8192 halves = 4096 u32)
  {
    unsigned int* hz = (unsigned int*)hbase;
    #pragma unroll
    for (int i=0;i<8;i++) hz[tid + i*512] = 0u;
  }
  float cc[4] = {0.f,0.f,0.f,0.f};
  _Float16 rh[4] = {(_Float16)0.f,(_Float16)0.f,(_Float16)0.f,(_Float16)0.f};
  _Float16 rl[4] = {(_Float16)0.f,(_Float16)0.f,(_Float16)0.f,(_Float16)0.f};
  __syncthreads();

  #pragma unroll 2
  for (int t=0; t<T_; ++t){
    const int cur = t & 1, nxt = cur ^ 1;
    const unsigned int mw = ml[t];

    // x for this lane's 4 rows (rows>=8 read wrapped; results unused)
    float4 xv0 = xsh[t][(r0+0)&7];
    float4 xv1 = xsh[t][(r0+1)&7];
    float4 xv2 = xsh[t][(r0+2)&7];
    float4 xv3 = xsh[t][(r0+3)&7];

    f32x4 acc[4];
    #pragma unroll
    for (int n=0;n<4;n++){
      acc[n][0] = bb[n] + mvn[n].x*xv0.x + mvn[n].y*xv0.y + mvn[n].z*xv0.z + mvn[n].w*xv0.w;
      acc[n][1] = bb[n] + mvn[n].x*xv1.x + mvn[n].y*xv1.y + mvn[n].z*xv1.z + mvn[n].w*xv1.w;
      acc[n][2] = bb[n] + mvn[n].x*xv2.x + mvn[n].y*xv2.y + mvn[n].z*xv2.z + mvn[n].w*xv2.w;
      acc[n][3] = bb[n] + mvn[n].x*xv3.x + mvn[n].y*xv3.y + mvn[n].z*xv3.z + mvn[n].w*xv3.w;
    }

    // A fragments: h hi/lo
    half8 ah[4], al[4];
    #pragma unroll
    for (int kt=0;kt<4;kt++){
      ah[kt] = *(const half8*)&hA[cur][0][kt][l][0];
      al[kt] = *(const half8*)&hA[cur][1][kt][l][0];
    }

    // 8 virtual k-passes (hi 0..3, lo 0..3), n inner for dep spacing 4
    #pragma unroll
    for (int v=0;v<8;v++){
      const half8 av = (v < 4) ? ah[v] : al[v-4];
      const int kt = v & 3;
      #pragma unroll
      for (int n=0;n<4;n++)
        acc[n] = __builtin_amdgcn_mfma_f32_16x16x32_f16(av, bw[n][kt], acc[n], 0, 0, 0);
    }

    // in-register activation; lane owns (rows r0..r0+3, unit u)
    #pragma unroll
    for (int i=0;i<4;i++){
      const float ig = acc[0][i], fg = acc[1][i], gv = acc[2][i], og = acc[3][i];
      const float cn = sigm(fg)*cc[i] + sigm(ig)*tanh_fast(gv);
      const float hn = sigm(og)*tanh_fast(cn);
      const int mb = (mw >> ((r0+i) & 7)) & 1;
      const _Float16 nh = (_Float16)hn;
      const _Float16 nl = (_Float16)(hn - (float)nh);
      cc[i] = mb ? cn : cc[i];
      rh[i] = mb ? nh : rh[i];
      rl[i] = mb ? nl : rl[i];
      hbase[nxt*4096 +    0 + hoff[i]] = rh[i];
      hbase[nxt*4096 + 2048 + hoff[i]] = rl[i];
    }
    __syncthreads();
  }

  // output this lane's own cells from registers (rows 0..7 real)
  float* hout = lstm ? h_s_out : h_t_out;
  if (l < 32){
    #pragma unroll
    for (int i=0;i<4;i++){
      const int row = r0 + i;                // 0..7
      hout[(n0+row)*H_ + u] = (float)rh[i] + (float)rl[i];
    }
  }
}

// ---------------- Kernel 2: fused = relu(relu([h_t,h_s]@F1T+f1)@F2T+f2) * ok ----------------
__global__ __launch_bounds__(128) void fuse_kernel(
    const float* __restrict__ h_t, const float* __restrict__ h_s,
    const float* __restrict__ F1T, const float* __restrict__ f1,
    const float* __restrict__ F2T, const float* __restrict__ f2,
    const float* __restrict__ okb, float* __restrict__ fused)
{
  const int n = blockIdx.x, j = threadIdx.x;
  __shared__ float comb[2*H_];
  __shared__ float hid[H_];
  comb[j]      = h_t[n*H_+j];
  comb[H_+j]   = h_s[n*H_+j];
  __syncthreads();
  float acc = f1[j];
  #pragma unroll 8
  for (int k=0;k<2*H_;k++) acc += comb[k]*F1T[k*H_+j];
  hid[j] = fmaxf(acc, 0.f);
  __syncthreads();
  float acc2 = f2[j];
  #pragma unroll 8
  for (int k=0;k<H_;k++) acc2 += hid[k]*F2T[k*H_+j];
  fused[n*H_+j] = fmaxf(acc2, 0.f) * okb[n];
}

// ---------------- Kernel 3a: per-batch mean of fused over valid rows ----------------
__global__ __launch_bounds__(128) void mean_kernel(
    const float* __restrict__ fused, const float* __restrict__ okb,
    float* __restrict__ mean)
{
  const int b = blockIdx.x, j = threadIdx.x;
  float s = 0.f;
  #pragma unroll 8
  for (int p=0;p<P_;p++) s += fused[(b*P_+p)*H_ + j];   // invalid rows already 0
  float nv = 0.f;
  #pragma unroll
  for (int p=0;p<P_;p++) nv += okb[b*P_+p];
  mean[b*H_+j] = s / fmaxf(nv, 1.f);
}

// ---------------- Kernel 3b: score per row (one block per (b,p)) ----------------
__global__ __launch_bounds__(128) void score_kernel(
    const float* __restrict__ fused, const float* __restrict__ mean,
    const float* __restrict__ okb,
    const float* __restrict__ A1T, const float* __restrict__ a1,
    const float* __restrict__ A2, const float* __restrict__ a2v,
    float* __restrict__ score)
{
  const int n = blockIdx.x, b = n >> 5, j = threadIdx.x;
  __shared__ float comb[2*H_];
  __shared__ float red[2];
  comb[j]      = fused[n*H_ + j];
  comb[H_+j]   = mean[b*H_ + j];
  __syncthreads();
  float acc = a1[j];
  #pragma unroll 8
  for (int k=0;k<2*H_;k++) acc += comb[k]*A1T[k*H_+j];
  float v = fmaxf(acc, 0.f) * A2[j];
  // reduce within each 64-lane wave, then across the 2 waves via LDS
  #pragma unroll
  for (int off=32; off>=1; off>>=1) v += __shfl_down(v, off, 64);
  if ((j & 63) == 0) red[j >> 6] = v;
  __syncthreads();
  if (j == 0){
    const float s = fmaxf(red[0] + red[1] + a2v[0], 0.f);
    score[n] = (okb[n] > 0.f) ? s : -1e9f;
  }
}

// ---------------- Kernel 3c: softmax over rows + weighted sum ----------------
__global__ __launch_bounds__(128) void final_kernel(
    const float* __restrict__ fused, const float* __restrict__ score,
    const float* __restrict__ okb, float* __restrict__ out)
{
  const int b = blockIdx.x, j = threadIdx.x;
  __shared__ float wgt[P_];
  if (j < P_){
    const float s = score[b*P_+j];
    const float ok = okb[b*P_+j];
    float mx = s;
    #pragma unroll
    for (int off=16; off>=1; off>>=1) mx = fmaxf(mx, __shfl_xor(mx, off, 32));
    float e = (ok > 0.f) ? __expf(s - mx) : 0.f;
    float se = e;
    #pragma unroll
    for (int off=16; off>=1; off>>=1) se += __shfl_xor(se, off, 32);
    wgt[j] = e / fmaxf(se, 1e-9f);
  }
  __syncthreads();
  float acc = 0.f;
  #pragma unroll 8
  for (int p=0;p<P_;p++) acc += wgt[p]*fused[(b*P_+p)*H_ + j];
  out[b*H_+j] = acc;
}

extern "C" void kernel_launch(void* const* d_in, const int* in_sizes, int n_in,
                              void* d_out, int out_size, void* d_ws, size_t ws_size,
                              hipStream_t stream) {
  const float* rel   = (const float*)d_in[1];
  const float* pvx   = (const float*)d_in[2];
  const float* pvy   = (const float*)d_in[3];
  const float* pax   = (const float*)d_in[4];
  const float* pay   = (const float*)d_in[5];
  const int*   pmask = (const int*)  d_in[6];
  const float* W_sp  = (const float*)d_in[7];
  const float* b_sp  = (const float*)d_in[8];
  const float* W_st  = (const float*)d_in[9];
  const float* b_st  = (const float*)d_in[10];
  const float* Wih_t = (const float*)d_in[11];
  const float* Whh_t = (const float*)d_in[12];
  const float* bih_t = (const float*)d_in[13];
  const float* bhh_t = (const float*)d_in[14];
  const float* Wih_s = (const float*)d_in[15];
  const float* Whh_s = (const float*)d_in[16];
  const float* bih_s = (const float*)d_in[17];
  const float* bhh_s = (const float*)d_in[18];
  const float* A1    = (const float*)d_in[19];
  const float* a1    = (const float*)d_in[20];
  const float* A2    = (const float*)d_in[21];
  const float* a2v   = (const float*)d_in[22];
  const float* F1    = (const float*)d_in[23];
  const float* f1    = (const float*)d_in[24];
  const float* F2    = (const float*)d_in[25];
  const float* f2    = (const float*)d_in[26];

  float* ws = (float*)d_ws;
  size_t off = 0;
  _Float16* Wfrag = (_Float16*)(ws + off); off += 65536;   // 131072 f16
  float* M4_t   = ws + off; off += (size_t)G_*4;
  float* M4_s   = ws + off; off += (size_t)G_*4;
  float* bias_t = ws + off; off += G_;
  float* bias_s = ws + off; off += G_;
  float* F1T    = ws + off; off += (size_t)2*H_*H_;
  float* F2T    = ws + off; off += (size_t)H_*H_;
  float* A1T    = ws + off; off += (size_t)2*H_*H_;
  float* h_t    = ws + off; off += (size_t)N_*H_;
  float* h_s    = ws + off; off += (size_t)N_*H_;
  float* fusedb = ws + off; off += (size_t)N_*H_;
  float* meanb  = ws + off; off += (size_t)B_*H_;
  float* scoreb = ws + off; off += N_;
  float* okb    = ws + off; off += N_;

  hipLaunchKernelGGL(prep_kernel, dim3(16), dim3(256), 0, stream,
      W_sp, b_sp, W_st, b_st, Wih_t, Whh_t, bih_t, bhh_t,
      Wih_s, Whh_s, bih_s, bhh_s, F1, F2, A1, pmask,
      M4_t, bias_t, M4_s, bias_s, Wfrag, F1T, F2T, A1T, okb);

  hipLaunchKernelGGL(lstm_kernel, dim3(N_/8, 2), dim3(512), 0, stream,
      rel, pvx, pvy, pax, pay, pmask,
      M4_t, bias_t, M4_s, bias_s, Wfrag,
      h_t, h_s);

  hipLaunchKernelGGL(fuse_kernel, dim3(N_), dim3(128), 0, stream,
      h_t, h_s, F1T, f1, F2T, f2, okb, fusedb);

  hipLaunchKernelGGL(mean_kernel, dim3(B_), dim3(128), 0, stream,
      fusedb, okb, meanb);

  hipLaunchKernelGGL(score_kernel, dim3(N_), dim3(128), 0, stream,
      fusedb, meanb, okb, A1T, a1, A2, a2v, scoreb);

  hipLaunchKernelGGL(final_kernel, dim3(B_), dim3(128), 0, stream,
      fusedb, scoreb, okb, (float*)d_out);
}

// Round 7
// 101.623 us; speedup vs baseline: 34.2732x; 1.4785x over previous
//
#include <hip/hip_runtime.h>

#define T_ 64
#define B_ 32
#define P_ 32
#define N_ 1024
#define H_ 128
#define G_ 512   // 4*H

typedef __attribute__((ext_vector_type(8))) _Float16 half8;
typedef __attribute__((ext_vector_type(4))) float f32x4;

__device__ __forceinline__ float rcpf(float x){ return __builtin_amdgcn_rcpf(x); }
__device__ __forceinline__ float sigm(float x){ return rcpf(1.f+__expf(-x)); }
__device__ __forceinline__ float tanh_fast(float x){ return 1.f - 2.f*rcpf(__expf(2.f*x)+1.f); }

// ---------------- Kernel 0: prep ----------------
// blk 0: Bx fragments (x-projection M4 + bias hi/lo folded as k-slots 0..5)
// blk 1-8: W fragments, f16, MFMA B-layout: [L][w][n][t][lane][j]
//          g = n*128 + w*16 + (lane&15), k = t*32 + 8*(lane>>4) + j
// blk 9: F1T, blk 10: F2T, blk 15: A1T, blk 11-14: okb
__global__ __launch_bounds__(256) void prep_kernel(
    const float* __restrict__ W_sp, const float* __restrict__ b_sp,
    const float* __restrict__ W_st, const float* __restrict__ b_st,
    const float* __restrict__ Wih_t, const float* __restrict__ Whh_t,
    const float* __restrict__ bih_t, const float* __restrict__ bhh_t,
    const float* __restrict__ Wih_s, const float* __restrict__ Whh_s,
    const float* __restrict__ bih_s, const float* __restrict__ bhh_s,
    const float* __restrict__ F1, const float* __restrict__ F2,
    const float* __restrict__ A1,
    const int* __restrict__ maskI,
    _Float16* __restrict__ Wfrag, _Float16* __restrict__ Bxfrag,
    float* __restrict__ F1T, float* __restrict__ F2T,
    float* __restrict__ A1T,
    float* __restrict__ okb)
{
  const int tid = threadIdx.x;
  const int blk = blockIdx.x;
  if (blk == 0) {
    // zero the whole Bx region first (lanes>=16 and j=6,7 must be 0)
    unsigned int* bz = (unsigned int*)Bxfrag;
    for (int i = tid; i < 16384; i += 256) bz[i] = 0u;
    __syncthreads();
    for (int g = tid; g < G_; g += 256) {
      const int wv = (g & 127) >> 4, n = g >> 7, lane = g & 15;
      // lstm 0 (traj): M = Wih_t @ W_sp (G x 2), bias = Wih_t@b_sp + bih + bhh
      {
        float m0=0.f,m1=0.f,bt=0.f;
        for (int e=0;e<H_;e++){ float wgt=Wih_t[g*H_+e]; m0+=wgt*W_sp[e*2]; m1+=wgt*W_sp[e*2+1]; bt+=wgt*b_sp[e]; }
        const float bsum = bt + bih_t[g] + bhh_t[g];
        _Float16* dst = Bxfrag + (((0*8+wv)*4+n)*64 + lane)*8;
        dst[0]=(_Float16)m0; dst[1]=(_Float16)m1; dst[2]=(_Float16)0.f; dst[3]=(_Float16)0.f;
        const _Float16 bh = (_Float16)bsum;
        dst[4]=bh; dst[5]=(_Float16)(bsum-(float)bh);
      }
      // lstm 1 (state): M = Wih_s @ W_st (G x 4)
      {
        float s0=0.f,s1=0.f,s2=0.f,s3=0.f,bs=0.f;
        for (int e=0;e<H_;e++){ float wgt=Wih_s[g*H_+e]; s0+=wgt*W_st[e*4]; s1+=wgt*W_st[e*4+1]; s2+=wgt*W_st[e*4+2]; s3+=wgt*W_st[e*4+3]; bs+=wgt*b_st[e]; }
        const float bsum = bs + bih_s[g] + bhh_s[g];
        _Float16* dst = Bxfrag + (((1*8+wv)*4+n)*64 + lane)*8;
        dst[0]=(_Float16)s0; dst[1]=(_Float16)s1; dst[2]=(_Float16)s2; dst[3]=(_Float16)s3;
        const _Float16 bh = (_Float16)bsum;
        dst[4]=bh; dst[5]=(_Float16)(bsum-(float)bh);
      }
    }
  } else if (blk <= 8) {
    const int L = (blk-1) >> 2;           // lstm
    const int q = (blk-1) & 3;            // quarter
    const float* Whh = L ? Whh_s : Whh_t;
    for (int e = q*16384 + tid; e < (q+1)*16384; e += 256) {
      const int j  = e & 7;
      const int l  = (e >> 3) & 63;
      const int t  = (e >> 9) & 3;
      const int n  = (e >> 11) & 3;
      const int w  = (e >> 13) & 7;
      const int g  = n*128 + w*16 + (l & 15);
      const int k  = t*32 + 8*(l >> 4) + j;
      Wfrag[L*65536 + e] = (_Float16)Whh[g*H_ + k];
    }
  } else if (blk == 9) {
    for (int idx = tid; idx < H_*2*H_; idx += 256) { // F1 (128,256)
      int j = idx >> 8, k = idx & 255;
      F1T[k*H_+j] = F1[idx];
    }
  } else if (blk == 10) {
    for (int idx = tid; idx < H_*H_; idx += 256) {  // F2 (128,128)
      int j = idx >> 7, k = idx & 127;
      F2T[k*H_+j] = F2[idx];
    }
  } else if (blk == 15) {
    for (int idx = tid; idx < H_*2*H_; idx += 256) { // A1 (128,256)
      int j = idx >> 8, k = idx & 255;
      A1T[k*H_+j] = A1[idx];
    }
  } else {
    const int n = (blk-11)*256 + tid;
    int cnt = 0;
    for (int t=0;t<T_;t++) cnt += (maskI[t*N_ + n] > 0);
    okb[n] = (cnt >= 2) ? 1.f : 0.f;
  }
}

// ---------------- Kernel 1: both masked LSTMs, MFMA ----------------
// grid (128, 2). 512 threads = 8 waves. Wave w owns units u=w*16+(l&15),
// ntile n = gate type (i,f,g,o). C rows 0-7 real, 8-15 pad.
// Per step: acc[n] = mfma(ax, bx[n], 0)  (x + bias via k-slots)
//           + 4 kt h-MFMAs (h stored f16-only in LDS A-frag layout, dbuf).
// Activation split: shfl_xor moves acc rows r0+2,r0+3 to the upper half-wave
// so every lane activates exactly 2 REAL cells (rows 0-7), halving the
// transcendental issue (the R6 VALU bottleneck).
__global__ __launch_bounds__(512) __attribute__((amdgpu_waves_per_eu(2,2)))
void lstm_kernel(
    const float* __restrict__ rel, const float* __restrict__ pvx,
    const float* __restrict__ pvy, const float* __restrict__ pax,
    const float* __restrict__ pay, const int* __restrict__ maskI,
    const _Float16* __restrict__ Wfrag, const _Float16* __restrict__ Bxfrag,
    float* __restrict__ h_t_out, float* __restrict__ h_s_out)
{
  __shared__ _Float16 hA[2][4][64][8] __align__(16);   // h f16, dbuf, 8KB
  __shared__ _Float16 axf[T_][16][8] __align__(16);    // x A-frags, 16KB
  __shared__ _Float16 zslot[8] __align__(16);
  __shared__ unsigned int ml[T_];

  const int lstm = blockIdx.y;
  const int tid  = threadIdx.x;
  const int w    = tid >> 6;
  const int l    = tid & 63;
  const int n0   = blockIdx.x * 8;
  const int u    = w*16 + (l & 15);
  const int kt_u = u >> 5;

  // ---- load B fragments: weights (4n x 4kt) + x/bias (4n) ----
  half8 bw[4][4], bx[4];
  #pragma unroll
  for (int n=0;n<4;n++){
    #pragma unroll
    for (int t=0;t<4;t++){
      const int base = ((((lstm*8 + w)*4 + n)*4 + t)*64 + l)*8;
      bw[n][t] = *(const half8*)(Wfrag + base);
    }
    bx[n] = *(const half8*)(Bxfrag + (((lstm*8 + w)*4 + n)*64 + l)*8);
  }

  // ---- stage x A-frags (rows 0-7 real, 8-15 zero) + mask ----
  {
    const int t = tid >> 3, r = tid & 7;
    const int n = n0 + r, b = n >> 5, p = n & 31;
    float x0,x1,x2,x3;
    if (lstm == 0){
      x0 = rel[(t*B_+b)*64 + p]; x1 = rel[(t*B_+b)*64 + 32 + p];
      x2 = 0.f; x3 = 0.f;
    } else {
      const int i0 = t*N_ + n;
      x0 = pvx[i0]; x1 = pvy[i0]; x2 = pax[i0]; x3 = pay[i0];
    }
    half8 v;
    v[0]=(_Float16)x0; v[1]=(_Float16)x1; v[2]=(_Float16)x2; v[3]=(_Float16)x3;
    v[4]=(_Float16)1.f; v[5]=(_Float16)1.f; v[6]=(_Float16)0.f; v[7]=(_Float16)0.f;
    *(half8*)&axf[t][r][0] = v;
    half8 zz;
    #pragma unroll
    for (int q=0;q<8;q++) zz[q]=(_Float16)0.f;
    *(half8*)&axf[t][8+r][0] = zz;
    if (tid == 0) *(half8*)&zslot[0] = zz;
    if (tid < T_){
      unsigned int mw = 0;
      for (int rr=0; rr<8; rr++) mw |= (maskI[tid*N_ + n0 + rr] > 0) ? (1u<<rr) : 0u;
      ml[tid] = mw;
    }
  }
  // zero both h buffers (4096 f16 = 2048 u32)
  {
    unsigned int* hz = (unsigned int*)&hA[0][0][0][0];
    #pragma unroll
    for (int i=0;i<4;i++) hz[tid + i*512] = 0u;
  }

  // activation ownership: 2 real cells per lane
  const int halfw = l >> 5;
  const int rbase = ((l & 31) >> 4)*4 + 2*halfw;      // rows rbase, rbase+1 (0..7)
  const int lpp0  = rbase + 16*((u >> 3) & 3);
  const int hoff0 = kt_u*512 + lpp0*8 + (u & 7);      // halves
  const int hoff1 = hoff0 + 8;                         // row+1 -> lpp+1
  _Float16* hbase = &hA[0][0][0][0];
  const _Float16* axp_base = (l < 16) ? &axf[0][l][0] : &zslot[0];
  const int ax_stride = (l < 16) ? 128 : 0;            // halves per t

  float cc0 = 0.f, cc1 = 0.f;
  _Float16 rh0 = (_Float16)0.f, rh1 = (_Float16)0.f;
  __syncthreads();

  const f32x4 zc = {0.f, 0.f, 0.f, 0.f};
  #pragma unroll 2
  for (int t=0; t<T_; ++t){
    const int cur = t & 1, nxt = cur ^ 1;
    const unsigned int mw = ml[t];

    // acc init via MFMA: x (k0-3) + bias hi/lo (k4-5)
    const half8 ax = *(const half8*)(axp_base + t*ax_stride);
    f32x4 acc[4];
    #pragma unroll
    for (int n=0;n<4;n++)
      acc[n] = __builtin_amdgcn_mfma_f32_16x16x32_f16(ax, bx[n], zc, 0, 0, 0);

    // h fragments (f16-only)
    half8 ah[4];
    #pragma unroll
    for (int kt=0;kt<4;kt++) ah[kt] = *(const half8*)&hA[cur][kt][l][0];

    #pragma unroll
    for (int kt=0;kt<4;kt++)
      #pragma unroll
      for (int n=0;n<4;n++)
        acc[n] = __builtin_amdgcn_mfma_f32_16x16x32_f16(ah[kt], bw[n][kt], acc[n], 0, 0, 0);

    // redistribute: upper half-wave takes rows r0+2,r0+3 from lower half
    float g0[4], g1[4];
    #pragma unroll
    for (int n=0;n<4;n++){
      const float s2 = __shfl_xor(acc[n][2], 32, 64);
      const float s3 = __shfl_xor(acc[n][3], 32, 64);
      g0[n] = halfw ? s2 : acc[n][0];
      g1[n] = halfw ? s3 : acc[n][1];
    }

    // two real-cell activations (gate order: 0=i,1=f,2=g,3=o)
    {
      const float cn = sigm(g0[1])*cc0 + sigm(g0[0])*tanh_fast(g0[2]);
      const float hn = sigm(g0[3])*tanh_fast(cn);
      const int mb = (mw >> rbase) & 1;
      cc0 = mb ? cn : cc0;
      rh0 = mb ? (_Float16)hn : rh0;
      hbase[nxt*2048 + hoff0] = rh0;
    }
    {
      const float cn = sigm(g1[1])*cc1 + sigm(g1[0])*tanh_fast(g1[2]);
      const float hn = sigm(g1[3])*tanh_fast(cn);
      const int mb = (mw >> (rbase+1)) & 1;
      cc1 = mb ? cn : cc1;
      rh1 = mb ? (_Float16)hn : rh1;
      hbase[nxt*2048 + hoff1] = rh1;
    }
    __syncthreads();
  }

  // output this lane's two cells
  float* hout = lstm ? h_s_out : h_t_out;
  hout[(n0 + rbase    )*H_ + u] = (float)rh0;
  hout[(n0 + rbase + 1)*H_ + u] = (float)rh1;
}

// ---------------- Kernel 2: fused = relu(relu([h_t,h_s]@F1T+f1)@F2T+f2) * ok ----------------
__global__ __launch_bounds__(128) void fuse_kernel(
    const float* __restrict__ h_t, const float* __restrict__ h_s,
    const float* __restrict__ F1T, const float* __restrict__ f1,
    const float* __restrict__ F2T, const float* __restrict__ f2,
    const float* __restrict__ okb, float* __restrict__ fused)
{
  const int n = blockIdx.x, j = threadIdx.x;
  __shared__ float comb[2*H_];
  __shared__ float hid[H_];
  comb[j]      = h_t[n*H_+j];
  comb[H_+j]   = h_s[n*H_+j];
  __syncthreads();
  float acc = f1[j];
  #pragma unroll 8
  for (int k=0;k<2*H_;k++) acc += comb[k]*F1T[k*H_+j];
  hid[j] = fmaxf(acc, 0.f);
  __syncthreads();
  float acc2 = f2[j];
  #pragma unroll 8
  for (int k=0;k<H_;k++) acc2 += hid[k]*F2T[k*H_+j];
  fused[n*H_+j] = fmaxf(acc2, 0.f) * okb[n];
}

// ---------------- Kernel 3a: per-batch mean of fused over valid rows ----------------
__global__ __launch_bounds__(128) void mean_kernel(
    const float* __restrict__ fused, const float* __restrict__ okb,
    float* __restrict__ mean)
{
  const int b = blockIdx.x, j = threadIdx.x;
  float s = 0.f;
  #pragma unroll 8
  for (int p=0;p<P_;p++) s += fused[(b*P_+p)*H_ + j];   // invalid rows already 0
  float nv = 0.f;
  #pragma unroll
  for (int p=0;p<P_;p++) nv += okb[b*P_+p];
  mean[b*H_+j] = s / fmaxf(nv, 1.f);
}

// ---------------- Kernel 3b: score per row (one block per (b,p)) ----------------
__global__ __launch_bounds__(128) void score_kernel(
    const float* __restrict__ fused, const float* __restrict__ mean,
    const float* __restrict__ okb,
    const float* __restrict__ A1T, const float* __restrict__ a1,
    const float* __restrict__ A2, const float* __restrict__ a2v,
    float* __restrict__ score)
{
  const int n = blockIdx.x, b = n >> 5, j = threadIdx.x;
  __shared__ float comb[2*H_];
  __shared__ float red[2];
  comb[j]      = fused[n*H_ + j];
  comb[H_+j]   = mean[b*H_ + j];
  __syncthreads();
  float acc = a1[j];
  #pragma unroll 8
  for (int k=0;k<2*H_;k++) acc += comb[k]*A1T[k*H_+j];
  float v = fmaxf(acc, 0.f) * A2[j];
  #pragma unroll
  for (int off=32; off>=1; off>>=1) v += __shfl_down(v, off, 64);
  if ((j & 63) == 0) red[j >> 6] = v;
  __syncthreads();
  if (j == 0){
    const float s = fmaxf(red[0] + red[1] + a2v[0], 0.f);
    score[n] = (okb[n] > 0.f) ? s : -1e9f;
  }
}

// ---------------- Kernel 3c: softmax over rows + weighted sum ----------------
__global__ __launch_bounds__(128) void final_kernel(
    const float* __restrict__ fused, const float* __restrict__ score,
    const float* __restrict__ okb, float* __restrict__ out)
{
  const int b = blockIdx.x, j = threadIdx.x;
  __shared__ float wgt[P_];
  if (j < P_){
    const float s = score[b*P_+j];
    const float ok = okb[b*P_+j];
    float mx = s;
    #pragma unroll
    for (int off=16; off>=1; off>>=1) mx = fmaxf(mx, __shfl_xor(mx, off, 32));
    float e = (ok > 0.f) ? __expf(s - mx) : 0.f;
    float se = e;
    #pragma unroll
    for (int off=16; off>=1; off>>=1) se += __shfl_xor(se, off, 32);
    wgt[j] = e / fmaxf(se, 1e-9f);
  }
  __syncthreads();
  float acc = 0.f;
  #pragma unroll 8
  for (int p=0;p<P_;p++) acc += wgt[p]*fused[(b*P_+p)*H_ + j];
  out[b*H_+j] = acc;
}

extern "C" void kernel_launch(void* const* d_in, const int* in_sizes, int n_in,
                              void* d_out, int out_size, void* d_ws, size_t ws_size,
                              hipStream_t stream) {
  const float* rel   = (const float*)d_in[1];
  const float* pvx   = (const float*)d_in[2];
  const float* pvy   = (const float*)d_in[3];
  const float* pax   = (const float*)d_in[4];
  const float* pay   = (const float*)d_in[5];
  const int*   pmask = (const int*)  d_in[6];
  const float* W_sp  = (const float*)d_in[7];
  const float* b_sp  = (const float*)d_in[8];
  const float* W_st  = (const float*)d_in[9];
  const float* b_st  = (const float*)d_in[10];
  const float* Wih_t = (const float*)d_in[11];
  const float* Whh_t = (const float*)d_in[12];
  const float* bih_t = (const float*)d_in[13];
  const float* bhh_t = (const float*)d_in[14];
  const float* Wih_s = (const float*)d_in[15];
  const float* Whh_s = (const float*)d_in[16];
  const float* bih_s = (const float*)d_in[17];
  const float* bhh_s = (const float*)d_in[18];
  const float* A1    = (const float*)d_in[19];
  const float* a1    = (const float*)d_in[20];
  const float* A2    = (const float*)d_in[21];
  const float* a2v   = (const float*)d_in[22];
  const float* F1    = (const float*)d_in[23];
  const float* f1    = (const float*)d_in[24];
  const float* F2    = (const float*)d_in[25];
  const float* f2    = (const float*)d_in[26];

  float* ws = (float*)d_ws;
  size_t off = 0;
  _Float16* Wfrag  = (_Float16*)(ws + off); off += 65536;   // 131072 f16
  _Float16* Bxfrag = (_Float16*)(ws + off); off += 16384;   // 32768 f16
  float* F1T    = ws + off; off += (size_t)2*H_*H_;
  float* F2T    = ws + off; off += (size_t)H_*H_;
  float* A1T    = ws + off; off += (size_t)2*H_*H_;
  float* h_t    = ws + off; off += (size_t)N_*H_;
  float* h_s    = ws + off; off += (size_t)N_*H_;
  float* fusedb = ws + off; off += (size_t)N_*H_;
  float* meanb  = ws + off; off += (size_t)B_*H_;
  float* scoreb = ws + off; off += N_;
  float* okb    = ws + off; off += N_;

  hipLaunchKernelGGL(prep_kernel, dim3(16), dim3(256), 0, stream,
      W_sp, b_sp, W_st, b_st, Wih_t, Whh_t, bih_t, bhh_t,
      Wih_s, Whh_s, bih_s, bhh_s, F1, F2, A1, pmask,
      Wfrag, Bxfrag, F1T, F2T, A1T, okb);

  hipLaunchKernelGGL(lstm_kernel, dim3(N_/8, 2), dim3(512), 0, stream,
      rel, pvx, pvy, pax, pay, pmask,
      Wfrag, Bxfrag, h_t, h_s);

  hipLaunchKernelGGL(fuse_kernel, dim3(N_), dim3(128), 0, stream,
      h_t, h_s, F1T, f1, F2T, f2, okb, fusedb);

  hipLaunchKernelGGL(mean_kernel, dim3(B_), dim3(128), 0, stream,
      fusedb, okb, meanb);

  hipLaunchKernelGGL(score_kernel, dim3(N_), dim3(128), 0, stream,
      fusedb, meanb, okb, A1T, a1, A2, a2v, scoreb);

  hipLaunchKernelGGL(final_kernel, dim3(B_), dim3(128), 0, stream,
      fusedb, scoreb, okb, (float*)d_out);
}